// Round 9
// baseline (1323.430 us; speedup 1.0000x reference)
//
#include <hip/hip_runtime.h>
#include <math.h>

// Problem constants
#define BB 8
#define SS 2048
#define DM 512
#define DK 64
#define DFF 2048
#define ROWS (BB*SS)          // 16384
#define NTOT (ROWS*DM)        // 8388608
#define LN_EPS 1e-5
#define PAD_IDX 0

typedef __attribute__((ext_vector_type(8))) short short8;
typedef __attribute__((ext_vector_type(4))) short s16x4;
typedef __attribute__((ext_vector_type(4))) float f32x4;

__device__ __forceinline__ short f2b(float f) {        // fp32 -> bf16 (RNE)
    unsigned u = __float_as_uint(f);
    unsigned r = (u + 0x7fffu + ((u >> 16) & 1u)) >> 16;
    return (short)r;
}
__device__ __forceinline__ float b2f(short s) {        // bf16 -> fp32
    return __uint_as_float(((unsigned)(unsigned short)s) << 16);
}

// ---------------------------------------------------------------------------
// Embedding + positional encoding -> trunk T1 (bf16); zero LN stat slots
// ---------------------------------------------------------------------------
__global__ __launch_bounds__(256) void embed_kernel(const int* __restrict__ ids,
                                                    const float* __restrict__ emb,
                                                    short* __restrict__ T1,
                                                    double* __restrict__ red) {
    int idx = blockIdx.x * 256 + threadIdx.x;
    if (idx < 24) red[idx] = 0.0;              // 12 LN slots x (sum,sumsq)
    if (idx >= NTOT) return;
    int d   = idx & (DM - 1);
    int row = idx >> 9;
    int s   = row & (SS - 1);
    int id  = ids[row];
    float e = (id != PAD_IDX) ? emb[(size_t)id * DM + d] : 0.0f;
    float ex  = 2.0f * (float)d / 512.0f;
    float div = powf(10000.0f, ex);
    float arg = (float)s / div;
    float pe  = (d & 1) ? cosf(arg) : sinf(arg);
    T1[idx] = f2b(e + pe);
}

// ---------------------------------------------------------------------------
// Weight packing: WqkvT bf16 [256][512] (rows 192..255 zero) + bqkv fp32[256]
// ---------------------------------------------------------------------------
__global__ __launch_bounds__(256) void packqkvT_kernel(const float* __restrict__ Wq,
                                                       const float* __restrict__ Wk,
                                                       const float* __restrict__ Wv,
                                                       const float* __restrict__ bq,
                                                       const float* __restrict__ bk,
                                                       const float* __restrict__ bv,
                                                       short* __restrict__ WqkvT,
                                                       float* __restrict__ bqkv) {
    int i = blockIdx.x * 256 + threadIdx.x;
    if (i < 256 * 512) {
        int n = i >> 9, k = i & 511;
        float v = (n < 64)  ? Wq[k * 64 + n]
                : (n < 128) ? Wk[k * 64 + (n - 64)]
                : (n < 192) ? Wv[k * 64 + (n - 128)] : 0.0f;
        WqkvT[i] = f2b(v);
    }
    if (i < 256)
        bqkv[i] = (i < 64) ? bq[i] : (i < 128) ? bk[i - 64] : (i < 192) ? bv[i - 128] : 0.0f;
}

// WoST bf16 [512][64]: WoST[e][k] = sum_h Wo[h*64+k][e]
__global__ __launch_bounds__(256) void wosumT_kernel(const float* __restrict__ Wo,
                                                     short* __restrict__ WoST) {
    int i = blockIdx.x * 256 + threadIdx.x;
    if (i >= 512 * 64) return;
    int e = i >> 6, k = i & 63;
    float s = 0.f;
#pragma unroll
    for (int h = 0; h < 8; ++h) s += Wo[(size_t)(h * 64 + k) * 512 + e];
    WoST[i] = f2b(s);
}

// Tiled transpose fp32[R][C] -> bf16[C][R]
__global__ __launch_bounds__(256) void transpose_b16(const float* __restrict__ in,
                                                     short* __restrict__ out,
                                                     int R, int C) {
    __shared__ float tile[32][33];
    int bx = blockIdx.x * 32;
    int by = blockIdx.y * 32;
    int tx = threadIdx.x & 31, ty = threadIdx.x >> 5;
#pragma unroll
    for (int i = 0; i < 32; i += 8)
        tile[ty + i][tx] = in[(size_t)(by + ty + i) * C + bx + tx];
    __syncthreads();
#pragma unroll
    for (int i = 0; i < 32; i += 8)
        out[(size_t)(bx + ty + i) * R + by + tx] = f2b(tile[tx][ty + i]);
}

// Column sums of bf16 weights (for LN folding):
// csq[n<256] = sum_k WqkvT[n][k]; csw1[n<2048] = sum_k W1T[n][k]
__global__ __launch_bounds__(256) void colsum_kernel(const short* __restrict__ WqkvT,
                                                     const short* __restrict__ W1T,
                                                     float* __restrict__ csq,
                                                     float* __restrict__ csw1) {
    int i = blockIdx.x * 256 + threadIdx.x;
    if (i < 256) {
        const short* p = WqkvT + (size_t)i * 512;
        float s = 0.f;
        for (int k = 0; k < 512; ++k) s += b2f(p[k]);
        csq[i] = s;
    } else if (i < 2304) {
        int n = i - 256;
        const short* p = W1T + (size_t)n * 512;
        float s = 0.f;
        for (int k = 0; k < 512; ++k) s += b2f(p[k]);
        csw1[n] = s;
    }
}

// V slice of qkvb [16384][256] -> Vtg bf16 [8][64][2048]
__global__ __launch_bounds__(256) void vtrans_kernel(const short* __restrict__ qkvb,
                                                     short* __restrict__ Vtg) {
    __shared__ short tile[32][40];
    int sx = blockIdx.x * 32;
    int dy = blockIdx.y * 32;
    int b  = blockIdx.z;
    int tx = threadIdx.x & 31, ty = threadIdx.x >> 5;
#pragma unroll
    for (int i = 0; i < 32; i += 8)
        tile[ty + i][tx] = qkvb[(size_t)(b * SS + sx + ty + i) * 256 + 128 + dy + tx];
    __syncthreads();
#pragma unroll
    for (int i = 0; i < 32; i += 8)
        Vtg[(size_t)(b * 64 + dy + ty + i) * SS + sx + tx] = tile[tx][ty + i];
}

// ---------------------------------------------------------------------------
// bf16 MFMA GEMM, BMxBN tile, BK in {32,64}, NBUF in {2,3}, 256 thr = 4 waves.
// Round-8 post-mortem: the 3-buffer single-barrier rotation improved FF2
// (70.4->65.9us) but the simultaneous config flips regressed FF1 (BK=32, the
// twice-proven loser) and QKV/outproj (72KB 3buf -> 2 blk/CU vs 48KB 2buf ->
// 3 blk/CU). This round: RECOMBINE measured-best per call site via NBUF
// template param -- no new structure.
//   NBUF=2 (round-6 schedule): vmcnt(LPS)->barrier->ds_reads->lgkmcnt(0)->
//     barrier->stage(cur,+2)->MFMA.  QKV/outproj 64/128/64 (48KB, 3/CU);
//     FF1 128/128/64 (64KB, 2/CU).
//   NBUF=3 (round-8 schedule): vmcnt(LPS)->barrier->ds_reads->stage((cur+2)%3)
//     ->MFMA->lgkmcnt(0) [free: last MFMA already drained lgkm]. Single
//     barrier/step. FF2 64/256/32 (60KB, 2/CU, grid 512 = exact residency).
// XOR swizzle (conflict-free, verified rounds 2/5/8):
//  BK=32: stage row wv*16+(l>>2), src chunk (l&3)^((l>>3)&3); read slot
//         q^((l16>>1)&3).
//  BK=64: stage row wv*8+(l>>3), src chunk (l&7)^((l>>3)&7); read slot
//         (ks*4+q)^(l16&7).
// LN folding / STATS / RESID / FOLD semantics unchanged.
// ---------------------------------------------------------------------------
__device__ __forceinline__ void async16(const void* g, void* l) {
    __builtin_amdgcn_global_load_lds(
        (const __attribute__((address_space(1))) void*)g,
        (__attribute__((address_space(3))) void*)l, 16, 0, 0);
}

template <bool RELU, bool RESID, bool STATS, bool FOLD, int BM, int BN, int BK, int NBUF>
__global__ __launch_bounds__(256) void gemm_mfma(const short* __restrict__ A,
                                                 const short* __restrict__ BT,
                                                 const float* __restrict__ bias,
                                                 const float* __restrict__ colsum,
                                                 const short* __restrict__ residB,
                                                 short* __restrict__ C,
                                                 const double* __restrict__ statsIn,
                                                 double* __restrict__ statsOut,
                                                 int M, int N, int K) {
    constexpr int NT   = (BN == 256) ? 4 : ((BM == 128) ? 4 : 2);
    constexpr int KSUB = BK / 32;                    // 32-K sub-steps per tile
    constexpr int RPS  = (BK == 32) ? 64 : 32;       // rows per stage unit (256 lanes)
    constexpr int LPS  = (BM + BN) / RPS;            // loads/lane per staged tile
    __shared__ short As[NBUF][BM * BK];
    __shared__ short Bs[NBUF][BN * BK];
    const int t   = threadIdx.x;
    const int wv  = t >> 6;
    const int l   = t & 63;
    const int q   = l >> 4,  l16 = l & 15;
    const int mbase = (BM == 128) ? (wv >> 1) * 64 : 0;
    const int nbase = (BM == 128) ? (wv & 1) * 64
                    : ((BN == 256) ? wv * 64 : wv * 32);
    const long m0 = (long)blockIdx.x * BM;
    const long n0 = (long)blockIdx.y * BN;

    float muf = 0.f, rstdf = 1.f;
    if (FOLD || RESID) {
        if (statsIn) {
            double mean = statsIn[0] * (1.0 / NTOT);
            double var  = statsIn[1] * (1.0 / NTOT) - mean * mean;
            muf   = (float)mean;
            rstdf = (float)(1.0 / sqrt(var + LN_EPS));
        }
    }

    f32x4 acc[4][NT] = {};

    // staging geometry (see header comment)
    const int srow = (BK == 32) ? (wv * 16 + (l >> 2)) : (wv * 8 + (l >> 3));
    const int kcol = (BK == 32) ? (((l & 3) ^ ((l >> 3) & 3)) * 8)
                                : (((l & 7) ^ ((l >> 3) & 7)) * 8);
    const int wrow = (BK == 32) ? wv * 16 : wv * 8;  // wave's LDS base row

    auto stage = [&](int buf, int k0) {
#pragma unroll
        for (int i = 0; i < BM / RPS; ++i)
            async16(A + (m0 + srow + i * RPS) * (long)K + k0 + kcol,
                    &As[buf][(wrow + i * RPS) * BK + l * 8]);
#pragma unroll
        for (int i = 0; i < BN / RPS; ++i)
            async16(BT + (n0 + srow + i * RPS) * (long)K + k0 + kcol,
                    &Bs[buf][(wrow + i * RPS) * BK + l * 8]);
    };
    auto waitcnt_steady = [&]() {
        if constexpr (LPS == 4)       asm volatile("s_waitcnt vmcnt(4)" ::: "memory");
        else if constexpr (LPS == 5)  asm volatile("s_waitcnt vmcnt(5)" ::: "memory");
        else if constexpr (LPS == 6)  asm volatile("s_waitcnt vmcnt(6)" ::: "memory");
        else                          asm volatile("s_waitcnt vmcnt(8)" ::: "memory");
    };

    // prologue: up to two tiles in flight
    stage(0, 0);
    if (K > BK) stage(1, BK);
    int cur = 0;
    for (int k0 = 0; k0 < K; k0 += BK) {
        // counted wait: tile[cur] landed; tile cur+1's LPS loads stay in flight
        if (k0 + BK < K) waitcnt_steady();
        else             asm volatile("s_waitcnt vmcnt(0)" ::: "memory");
        __builtin_amdgcn_sched_barrier(0);
        __builtin_amdgcn_s_barrier();          // tile[cur] fully in LDS
        __builtin_amdgcn_sched_barrier(0);

        short8 af[KSUB][4], bfr[KSUB][NT];
#pragma unroll
        for (int ks = 0; ks < KSUB; ++ks) {
            const int slot = (BK == 32) ? (q ^ ((l16 >> 1) & 3))
                                        : ((ks * 4 + q) ^ (l16 & 7));
#pragma unroll
            for (int i = 0; i < 4; ++i)
                af[ks][i] = *(const short8*)&As[cur][(mbase + i * 16 + l16) * BK + slot * 8];
#pragma unroll
            for (int i = 0; i < NT; ++i)
                bfr[ks][i] = *(const short8*)&Bs[cur][(nbase + i * 16 + l16) * BK + slot * 8];
        }

        if constexpr (NBUF == 2) {
            // WAR barrier before re-staging the buffer we just read
            asm volatile("s_waitcnt lgkmcnt(0)" ::: "memory");
            __builtin_amdgcn_sched_barrier(0);
            __builtin_amdgcn_s_barrier();      // all reads done -> WAR-safe
            __builtin_amdgcn_sched_barrier(0);
            if (k0 + 2 * BK < K) stage(cur, k0 + 2 * BK);
        } else {
            // 3-buffer: stage target (cur+2)%3 is neither read nor in-flight
            if (k0 + 2 * BK < K) {
                int sb = cur + 2; if (sb >= 3) sb -= 3;
                stage(sb, k0 + 2 * BK);
            }
        }

        __builtin_amdgcn_s_setprio(1);
#pragma unroll
        for (int ks = 0; ks < KSUB; ++ks)
#pragma unroll
            for (int mt = 0; mt < 4; ++mt)
#pragma unroll
                for (int nt = 0; nt < NT; ++nt)
                    acc[mt][nt] = __builtin_amdgcn_mfma_f32_16x16x32_bf16(
                        af[ks][mt], bfr[ks][nt], acc[mt][nt], 0, 0, 0);
        __builtin_amdgcn_s_setprio(0);

        if constexpr (NBUF == 3) {
            // free drain: my reads of buf[cur] complete before the next step's
            // barrier, which precedes any wave's stage into (cur+2)%3 == cur-1.
            asm volatile("s_waitcnt lgkmcnt(0)" ::: "memory");
            __builtin_amdgcn_sched_barrier(0);
        }

        cur += 1; if (cur >= NBUF) cur = 0;
    }

    const float mr = muf * rstdf;
    float s = 0.f, sq = 0.f;
#pragma unroll
    for (int mt = 0; mt < 4; ++mt) {
        const long rowb = m0 + mbase + mt * 16 + q * 4;
#pragma unroll
        for (int nt = 0; nt < NT; ++nt) {
            const long col = n0 + nbase + nt * 16 + l16;
            const float bv = bias[col];
            const float cs = FOLD ? colsum[col] : 0.f;
#pragma unroll
            for (int r = 0; r < 4; ++r) {
                const long idx = (rowb + r) * (long)N + col;
                float v = acc[mt][nt][r];
                if (FOLD) v = rstdf * v + bv - mr * cs;
                else      v = v + bv;
                if (RESID) v += (b2f(residB[idx]) - muf) * rstdf;
                if (RELU)  v = fmaxf(v, 0.0f);
                if (STATS) { s += v; sq += v * v; }
                C[idx] = f2b(v);
            }
        }
    }
    if (STATS) {
#pragma unroll
        for (int o = 32; o; o >>= 1) {
            s  += __shfl_down(s, o);
            sq += __shfl_down(sq, o);
        }
        __syncthreads();               // all waves past their last LDS reads
        float* sm = (float*)As;        // safe to reuse buf0 as scratch now
        if (l == 0) { sm[wv] = s; sm[4 + wv] = sq; }
        __syncthreads();
        if (t == 0) {
            atomicAdd(&statsOut[0], (double)(sm[0] + sm[1] + sm[2] + sm[3]));
            atomicAdd(&statsOut[1], (double)(sm[4] + sm[5] + sm[6] + sm[7]));
        }
    }
}

// ---------------------------------------------------------------------------
// bf16 MFMA flash attention (unchanged).
// ---------------------------------------------------------------------------
__global__ __launch_bounds__(256) void attn_mfma(const short* __restrict__ qkvb,
                                                 const short* __restrict__ Vtg,
                                                 short* __restrict__ head) {
    const int b  = blockIdx.y;
    const int q0 = blockIdx.x * 64;
    const int t  = threadIdx.x;
    const int w  = t >> 6;
    const int l  = t & 63;
    const int l15 = l & 15, lq = l >> 4;
    const int l7  = l & 7,  l8 = l >> 3;

    __shared__ short Ks[64][72];
    __shared__ short Vs[64][72];
    __shared__ short Ps[4][16][68];

    short8 qf[2];
    {
        const short* qrow = qkvb + (size_t)(b * SS + q0 + w * 16 + l15) * 256;
        qf[0] = *(const short8*)(qrow + lq * 8);
        qf[1] = *(const short8*)(qrow + 32 + lq * 8);
    }

    f32x4 acc[4];
#pragma unroll
    for (int mt = 0; mt < 4; ++mt) acc[mt] = {0.f, 0.f, 0.f, 0.f};
    float m_i = -INFINITY, l_i = 0.f;
    const float sc = 0.0450712500463f;   // log2(e)/32

    short8 kreg[2], vreg[2];
    {
        const short* kb = qkvb + (size_t)(b * SS) * 256 + 64;
        kreg[0] = *(const short8*)(kb + (size_t)(w * 8 + l8) * 256 + l7 * 8);
        kreg[1] = *(const short8*)(kb + (size_t)(32 + w * 8 + l8) * 256 + l7 * 8);
        const short* vb = Vtg + (size_t)b * 64 * SS;
        vreg[0] = *(const short8*)(vb + (size_t)(w * 8 + l8) * SS + l7 * 8);
        vreg[1] = *(const short8*)(vb + (size_t)(32 + w * 8 + l8) * SS + l7 * 8);
    }

    for (int kt = 0; kt < SS / 64; ++kt) {
        __syncthreads();
        *(short8*)&Ks[w * 8 + l8][l7 * 8]      = kreg[0];
        *(short8*)&Ks[32 + w * 8 + l8][l7 * 8] = kreg[1];
        *(short8*)&Vs[w * 8 + l8][l7 * 8]      = vreg[0];
        *(short8*)&Vs[32 + w * 8 + l8][l7 * 8] = vreg[1];
        if (kt + 1 < SS / 64) {
            const short* kb = qkvb + (size_t)(b * SS + (kt + 1) * 64) * 256 + 64;
            kreg[0] = *(const short8*)(kb + (size_t)(w * 8 + l8) * 256 + l7 * 8);
            kreg[1] = *(const short8*)(kb + (size_t)(32 + w * 8 + l8) * 256 + l7 * 8);
            const short* vb = Vtg + (size_t)b * 64 * SS + (kt + 1) * 64;
            vreg[0] = *(const short8*)(vb + (size_t)(w * 8 + l8) * SS + l7 * 8);
            vreg[1] = *(const short8*)(vb + (size_t)(32 + w * 8 + l8) * SS + l7 * 8);
        }
        __syncthreads();

        f32x4 st[4];
#pragma unroll
        for (int mt = 0; mt < 4; ++mt) st[mt] = {0.f, 0.f, 0.f, 0.f};
#pragma unroll
        for (int kc = 0; kc < 2; ++kc)
#pragma unroll
            for (int mt = 0; mt < 4; ++mt) {
                short8 kf = *(const short8*)&Ks[mt * 16 + l15][kc * 32 + lq * 8];
                st[mt] = __builtin_amdgcn_mfma_f32_16x16x32_bf16(kf, qf[kc], st[mt], 0, 0, 0);
            }
        float mx = m_i;
#pragma unroll
        for (int mt = 0; mt < 4; ++mt)
#pragma unroll
            for (int r = 0; r < 4; ++r) {
                st[mt][r] *= sc;
                mx = fmaxf(mx, st[mt][r]);
            }
        mx = fmaxf(mx, __shfl_xor(mx, 16));
        mx = fmaxf(mx, __shfl_xor(mx, 32));
        float alpha = exp2f(m_i - mx);
        float rs = 0.f;
#pragma unroll
        for (int mt = 0; mt < 4; ++mt) {
            s16x4 pk;
#pragma unroll
            for (int r = 0; r < 4; ++r) {
                float p = exp2f(st[mt][r] - mx);
                rs += p;
                pk[r] = f2b(p);
            }
            *(s16x4*)&Ps[w][l15][mt * 16 + lq * 4] = pk;
        }
        rs += __shfl_xor(rs, 16);
        rs += __shfl_xor(rs, 32);
        l_i = l_i * alpha + rs;
        m_i = mx;
#pragma unroll
        for (int mt = 0; mt < 4; ++mt)
#pragma unroll
            for (int r = 0; r < 4; ++r) acc[mt][r] *= alpha;

#pragma unroll
        for (int kc = 0; kc < 2; ++kc) {
            s16x4 p0 = *(const s16x4*)&Ps[w][l15][kc * 32 + lq * 8];
            s16x4 p1 = *(const s16x4*)&Ps[w][l15][kc * 32 + lq * 8 + 4];
            short8 pf = __builtin_shufflevector(p0, p1, 0, 1, 2, 3, 4, 5, 6, 7);
#pragma unroll
            for (int mt = 0; mt < 4; ++mt) {
                short8 vf = *(const short8*)&Vs[mt * 16 + l15][kc * 32 + lq * 8];
                acc[mt] = __builtin_amdgcn_mfma_f32_16x16x32_bf16(vf, pf, acc[mt], 0, 0, 0);
            }
        }
    }
    float inv = 1.0f / l_i;
    short* out = head + (size_t)(b * SS + q0 + w * 16 + l15) * 64;
#pragma unroll
    for (int mt = 0; mt < 4; ++mt) {
        s16x4 o;
#pragma unroll
        for (int r = 0; r < 4; ++r) o[r] = f2b(acc[mt][r] * inv);
        *(s16x4*)&out[mt * 16 + lq * 4] = o;
    }
}

// ---------------------------------------------------------------------------
// Final LN2 normalize: d_out fp32 = (b2f(T1) - mu)*rstd
// ---------------------------------------------------------------------------
__global__ __launch_bounds__(256) void lnfinal_kernel(const short* __restrict__ y,
                                                      float* __restrict__ out,
                                                      const double* __restrict__ red,
                                                      int n) {
    double mean = red[0] / n;
    double var  = red[1] / n - mean * mean;
    float mu   = (float)mean;
    float rstd = (float)(1.0 / sqrt(var + LN_EPS));
    for (int i = blockIdx.x * blockDim.x + threadIdx.x; i < n;
         i += gridDim.x * blockDim.x)
        out[i] = (b2f(y[i]) - mu) * rstd;
}

// ---------------------------------------------------------------------------
extern "C" void kernel_launch(void* const* d_in, const int* in_sizes, int n_in,
                              void* d_out, int out_size, void* d_ws, size_t ws_size,
                              hipStream_t stream) {
    const int*   ids = (const int*)d_in[0];
    const float* emb = (const float*)d_in[1];
    const float* Wq  = (const float*)d_in[2];
    const float* bq  = (const float*)d_in[3];
    const float* Wk  = (const float*)d_in[4];
    const float* bk  = (const float*)d_in[5];
    const float* Wv  = (const float*)d_in[6];
    const float* bv  = (const float*)d_in[7];
    const float* Wo  = (const float*)d_in[8];
    const float* bo  = (const float*)d_in[9];
    const float* W1  = (const float*)d_in[10];
    const float* b1  = (const float*)d_in[11];
    const float* W2  = (const float*)d_in[12];
    const float* b2  = (const float*)d_in[13];

    float* xout = (float*)d_out;                     // final output only
    char* w = (char*)d_ws;

    // Buffers (bf16 unless noted):
    //   hch  [16384][2048] (full) or [8192][2048] (chunked) -- FF hidden
    //   qkvb [16384][256], Vtg [8][64][2048], head [16384][64]  (alias in hch)
    //   T1   trunk y (rep input / FF2 output), T2 trunk z (outproj output)
    const bool big = ws_size >= (size_t)105195712 + 256;

    short *qkvb, *Vtg, *head, *T1, *T2, *hch, *WqkvT, *WoST, *W1T, *W2T;
    float *bqkv, *csq, *csw1; double* red;

    if (big) {
        hch   = (short*)(w + 0);                     // 64 MB
        qkvb  = (short*)(w + 0);                     //  8 MB (alias)
        Vtg   = (short*)(w + 8388608);               //  2 MB (alias)
        head  = (short*)(w + 10485760);              //  2 MB (alias)
        T1    = (short*)(w + 67108864);              // 16 MB
        T2    = (short*)(w + 83886080);              // 16 MB
        WqkvT = (short*)(w + 100663296);
        bqkv  = (float*)(w + 100925440);
        csq   = (float*)(w + 100926464);
        WoST  = (short*)(w + 100927488);
        W1T   = (short*)(w + 100993024);
        csw1  = (float*)(w + 103090176);
        W2T   = (short*)(w + 103098368);
        red   = (double*)(w + 105195520);
    } else {
        hch   = (short*)(w + 0);                     // 32 MB (M=8192 chunks)
        qkvb  = (short*)(w + 0);
        Vtg   = (short*)(w + 8388608);
        head  = (short*)(w + 10485760);
        T1    = (short*)(w + 33554432);
        T2    = (short*)(w + 50331648);
        WqkvT = (short*)(w + 67108864);
        bqkv  = (float*)(w + 67371008);
        csq   = (float*)(w + 67372032);
        WoST  = (short*)(w + 67373056);
        W1T   = (short*)(w + 67438592);
        csw1  = (float*)(w + 69535744);
        W2T   = (short*)(w + 69543936);
        red   = (double*)(w + 71641088);
    }

    // ---- setup (once per launch) ----
    packqkvT_kernel<<<(256 * 512 + 255) / 256, 256, 0, stream>>>(Wq, Wk, Wv, bq, bk, bv, WqkvT, bqkv);
    wosumT_kernel<<<(512 * 64 + 255) / 256, 256, 0, stream>>>(Wo, WoST);
    transpose_b16<<<dim3(2048 / 32, 512 / 32), 256, 0, stream>>>(W1, W1T, 512, 2048);
    transpose_b16<<<dim3(512 / 32, 2048 / 32), 256, 0, stream>>>(W2, W2T, 2048, 512);
    colsum_kernel<<<9, 256, 0, stream>>>(WqkvT, W1T, csq, csw1);
    embed_kernel<<<NTOT / 256, 256, 0, stream>>>(ids, emb, T1, red);

    for (int rep = 0; rep < 6; ++rep) {
        const double* sprev = rep ? red + 4 * (rep - 1) + 2 : nullptr;  // LN2 stats of prev rep
        double* red1 = red + 4 * rep;        // LN1 stats (over z = outproj out)
        double* red2 = red + 4 * rep + 2;    // LN2 stats (over y' = FF2 out)

        // QKV: LN2-folded  qkvb = LN(T1) @ Wqkv + bqkv   [16384][256]
        gemm_mfma<false, false, false, true, 64, 128, 64, 2><<<dim3(256, 2), 256, 0, stream>>>(
            T1, WqkvT, bqkv, csq, nullptr, qkvb, sprev, nullptr, ROWS, 256, DM);
        // V transpose
        vtrans_kernel<<<dim3(SS / 32, 2, BB), 256, 0, stream>>>(qkvb, Vtg);
        // flash attention -> head
        attn_mfma<<<dim3(SS / 64, BB), 256, 0, stream>>>(qkvb, Vtg, head);
        // out-proj: T2 = head @ WoS + bo + LN(T1); stats -> red1
        gemm_mfma<false, true, true, false, 64, 128, 64, 2><<<dim3(256, 4), 256, 0, stream>>>(
            head, WoST, bo, nullptr, T1, T2, sprev, red1, ROWS, DM, DK);
        // FF (LN1 folded into FF1; resid LN1(T2) in FF2; stats -> red2)
        if (big) {
            gemm_mfma<true, false, false, true, 128, 128, 64, 2><<<dim3(128, 16), 256, 0, stream>>>(
                T2, W1T, b1, csw1, nullptr, hch, red1, nullptr, ROWS, DFF, DM);
            gemm_mfma<false, true, true, false, 64, 256, 32, 3><<<dim3(256, 2), 256, 0, stream>>>(
                hch, W2T, b2, nullptr, T2, T1, red1, red2, ROWS, DM, DFF);
        } else {
            for (int c = 0; c < 2; ++c) {
                const size_t off = (size_t)c * 8192 * DM;
                gemm_mfma<true, false, false, true, 128, 128, 64, 2><<<dim3(64, 16), 256, 0, stream>>>(
                    T2 + off, W1T, b1, csw1, nullptr, hch, red1, nullptr, 8192, DFF, DM);
                gemm_mfma<false, true, true, false, 64, 256, 32, 3><<<dim3(128, 2), 256, 0, stream>>>(
                    hch, W2T, b2, nullptr, T2 + off, T1 + off, red1, red2, 8192, DM, DFF);
            }
        }
    }
    // final LN2 normalize -> fp32 output
    lnfinal_kernel<<<4096, 256, 0, stream>>>(T1, xout, red + 4 * 5 + 2, NTOT);
}

// Round 10
// 1292.244 us; speedup vs baseline: 1.0241x; 1.0241x over previous
//
#include <hip/hip_runtime.h>
#include <math.h>

// Problem constants
#define BB 8
#define SS 2048
#define DM 512
#define DK 64
#define DFF 2048
#define ROWS (BB*SS)          // 16384
#define NTOT (ROWS*DM)        // 8388608
#define LN_EPS 1e-5
#define PAD_IDX 0

typedef __attribute__((ext_vector_type(8))) short short8;
typedef __attribute__((ext_vector_type(4))) short s16x4;
typedef __attribute__((ext_vector_type(4))) float f32x4;

__device__ __forceinline__ short f2b(float f) {        // fp32 -> bf16 (RNE)
    unsigned u = __float_as_uint(f);
    unsigned r = (u + 0x7fffu + ((u >> 16) & 1u)) >> 16;
    return (short)r;
}
__device__ __forceinline__ float b2f(short s) {        // bf16 -> fp32
    return __uint_as_float(((unsigned)(unsigned short)s) << 16);
}

// ---------------------------------------------------------------------------
// Embedding + positional encoding -> trunk T1 (bf16); zero LN stat slots
// ---------------------------------------------------------------------------
__global__ __launch_bounds__(256) void embed_kernel(const int* __restrict__ ids,
                                                    const float* __restrict__ emb,
                                                    short* __restrict__ T1,
                                                    double* __restrict__ red) {
    int idx = blockIdx.x * 256 + threadIdx.x;
    if (idx < 24) red[idx] = 0.0;              // 12 LN slots x (sum,sumsq)
    if (idx >= NTOT) return;
    int d   = idx & (DM - 1);
    int row = idx >> 9;
    int s   = row & (SS - 1);
    int id  = ids[row];
    float e = (id != PAD_IDX) ? emb[(size_t)id * DM + d] : 0.0f;
    float ex  = 2.0f * (float)d / 512.0f;
    float div = powf(10000.0f, ex);
    float arg = (float)s / div;
    float pe  = (d & 1) ? cosf(arg) : sinf(arg);
    T1[idx] = f2b(e + pe);
}

// ---------------------------------------------------------------------------
// Weight packing: WqkvT bf16 [256][512] (rows 192..255 zero) + bqkv fp32[256]
// ---------------------------------------------------------------------------
__global__ __launch_bounds__(256) void packqkvT_kernel(const float* __restrict__ Wq,
                                                       const float* __restrict__ Wk,
                                                       const float* __restrict__ Wv,
                                                       const float* __restrict__ bq,
                                                       const float* __restrict__ bk,
                                                       const float* __restrict__ bv,
                                                       short* __restrict__ WqkvT,
                                                       float* __restrict__ bqkv) {
    int i = blockIdx.x * 256 + threadIdx.x;
    if (i < 256 * 512) {
        int n = i >> 9, k = i & 511;
        float v = (n < 64)  ? Wq[k * 64 + n]
                : (n < 128) ? Wk[k * 64 + (n - 64)]
                : (n < 192) ? Wv[k * 64 + (n - 128)] : 0.0f;
        WqkvT[i] = f2b(v);
    }
    if (i < 256)
        bqkv[i] = (i < 64) ? bq[i] : (i < 128) ? bk[i - 64] : (i < 192) ? bv[i - 128] : 0.0f;
}

// WoST bf16 [512][64]: WoST[e][k] = sum_h Wo[h*64+k][e]
__global__ __launch_bounds__(256) void wosumT_kernel(const float* __restrict__ Wo,
                                                     short* __restrict__ WoST) {
    int i = blockIdx.x * 256 + threadIdx.x;
    if (i >= 512 * 64) return;
    int e = i >> 6, k = i & 63;
    float s = 0.f;
#pragma unroll
    for (int h = 0; h < 8; ++h) s += Wo[(size_t)(h * 64 + k) * 512 + e];
    WoST[i] = f2b(s);
}

// Tiled transpose fp32[R][C] -> bf16[C][R]
__global__ __launch_bounds__(256) void transpose_b16(const float* __restrict__ in,
                                                     short* __restrict__ out,
                                                     int R, int C) {
    __shared__ float tile[32][33];
    int bx = blockIdx.x * 32;
    int by = blockIdx.y * 32;
    int tx = threadIdx.x & 31, ty = threadIdx.x >> 5;
#pragma unroll
    for (int i = 0; i < 32; i += 8)
        tile[ty + i][tx] = in[(size_t)(by + ty + i) * C + bx + tx];
    __syncthreads();
#pragma unroll
    for (int i = 0; i < 32; i += 8)
        out[(size_t)(bx + ty + i) * R + by + tx] = f2b(tile[tx][ty + i]);
}

// Column sums of bf16 weights (for LN folding):
// csq[n<256] = sum_k WqkvT[n][k]; csw1[n<2048] = sum_k W1T[n][k]
__global__ __launch_bounds__(256) void colsum_kernel(const short* __restrict__ WqkvT,
                                                     const short* __restrict__ W1T,
                                                     float* __restrict__ csq,
                                                     float* __restrict__ csw1) {
    int i = blockIdx.x * 256 + threadIdx.x;
    if (i < 256) {
        const short* p = WqkvT + (size_t)i * 512;
        float s = 0.f;
        for (int k = 0; k < 512; ++k) s += b2f(p[k]);
        csq[i] = s;
    } else if (i < 2304) {
        int n = i - 256;
        const short* p = W1T + (size_t)n * 512;
        float s = 0.f;
        for (int k = 0; k < 512; ++k) s += b2f(p[k]);
        csw1[n] = s;
    }
}

// V slice of qkvb [16384][256] -> Vtg bf16 [8][64][2048]
__global__ __launch_bounds__(256) void vtrans_kernel(const short* __restrict__ qkvb,
                                                     short* __restrict__ Vtg) {
    __shared__ short tile[32][40];
    int sx = blockIdx.x * 32;
    int dy = blockIdx.y * 32;
    int b  = blockIdx.z;
    int tx = threadIdx.x & 31, ty = threadIdx.x >> 5;
#pragma unroll
    for (int i = 0; i < 32; i += 8)
        tile[ty + i][tx] = qkvb[(size_t)(b * SS + sx + ty + i) * 256 + 128 + dy + tx];
    __syncthreads();
#pragma unroll
    for (int i = 0; i < 32; i += 8)
        Vtg[(size_t)(b * 64 + dy + ty + i) * SS + sx + tx] = tile[tx][ty + i];
}

__device__ __forceinline__ void async16(const void* g, void* l) {
    __builtin_amdgcn_global_load_lds(
        (const __attribute__((address_space(1))) void*)g,
        (__attribute__((address_space(3))) void*)l, 16, 0, 0);
}

// ---------------------------------------------------------------------------
// FF1 8-phase 256x256 kernel (round-10). Port of the guide's verified 8-phase
// schedule to FF1 (M x 2048 = A[M,512] @ W1T[2048,512]^T, FOLD+RELU).
// 512 thr = 8 waves (2 M x 4 N), per-wave output 128x64, acc[8][4] f32x4.
// LDS 128KB: As[2][256*64] + Bs[2][256*64]; tile T -> buf T&1.
// Per tile, 4 phases (mq=p>>1, nq=p&1): each phase reads its fragment subtile
// (12 ds_read_b128 at nq=0: 8 A + 4 B; 4 at nq=1), stages tile T+1 quarters
// into buf ^b (A quarters at p=0, B quarters at p=1 -- front-loaded so the
// tile-boundary vmcnt(0) waits on calls >=2 phases old ~ already landed),
// then barrier; lgkm(0)+sched_barrier (rule 18); setprio(1); 16 MFMA;
// setprio(0); [p==3: vmcnt(0) BEFORE the closing barrier -> after that
// barrier, tile T+1 is visible chip-wide, so the next tile's phase-0 reads
// are safe pre-barrier]; barrier.
// Race invariants: stage only ever targets the buffer NOT being read this
// tile; all reads of buf ^b (tile T-1) were lgkm(0)-drained by each wave
// before T-1's closing barrier, which precedes any stage into ^b.
// Swizzle: identical to the verified BK=64 path (conflicts=0): stage thread t
// -> row t>>3, slot t&7, SOURCE chunk (t&7)^((t>>3)&7); read slot
// (ks*4+q)^(l16&7) (row&7==l16&7 since all row bases are multiples of 16).
// ---------------------------------------------------------------------------
__global__ __launch_bounds__(512) void gemm_ff1_8p(const short* __restrict__ A,
                                                   const short* __restrict__ BT,
                                                   const float* __restrict__ bias,
                                                   const float* __restrict__ colsum,
                                                   short* __restrict__ C,
                                                   const double* __restrict__ statsIn,
                                                   int M, int N) {
    constexpr int K = 512;
    constexpr int NTILE = K / 64;            // 8 K-tiles
    __shared__ short As[2][256 * 64];
    __shared__ short Bs[2][256 * 64];
    const int t   = threadIdx.x;
    const int wid = t >> 6;
    const int l   = t & 63;
    const int q   = l >> 4, l16 = l & 15;
    const int wm  = wid >> 2, wn = wid & 3;  // 2 x 4 wave grid
    const long m0 = (long)blockIdx.x * 256;
    const long n0 = (long)blockIdx.y * 256;

    float muf = 0.f, rstdf = 1.f;
    if (statsIn) {
        double mean = statsIn[0] * (1.0 / NTOT);
        double var  = statsIn[1] * (1.0 / NTOT) - mean * mean;
        muf   = (float)mean;
        rstdf = (float)(1.0 / sqrt(var + LN_EPS));
    }

    f32x4 acc[8][4] = {};

    const short* Ab = A  + m0 * K;
    const short* Bb = BT + n0 * K;
    const int srow = t >> 3;                          // 0..63 within a quarter
    const int kcol = ((t & 7) ^ ((t >> 3) & 7)) * 8;  // pre-swizzled src chunk
    const int rsl  = l16 & 7;                         // read-slot xor term

    // stage quarter j (64 rows) of K-tile T into buf b
    auto stageA = [&](int b, int T, int j) {
        async16(Ab + (long)(j * 64 + srow) * K + T * 64 + kcol,
                &As[b][j * 64 * 64 + t * 8]);
    };
    auto stageB = [&](int b, int T, int j) {
        async16(Bb + (long)(j * 64 + srow) * K + T * 64 + kcol,
                &Bs[b][j * 64 * 64 + t * 8]);
    };

    // prologue: tile 0 -> buf 0, fully drained
#pragma unroll
    for (int j = 0; j < 4; ++j) { stageA(0, 0, j); stageB(0, 0, j); }
    asm volatile("s_waitcnt vmcnt(0)" ::: "memory");
    __builtin_amdgcn_sched_barrier(0);
    __builtin_amdgcn_s_barrier();
    __builtin_amdgcn_sched_barrier(0);

    short8 af[4][2];                 // A frags persist across the 2 nq phases
    for (int T = 0; T < NTILE; ++T) {
        const int b = T & 1;
#pragma unroll
        for (int p = 0; p < 4; ++p) {
            const int mq = p >> 1, nq = p & 1;
            // ---- ds reads for this phase (buf b is stable this tile) ----
            if (nq == 0) {
#pragma unroll
                for (int i = 0; i < 4; ++i)
#pragma unroll
                    for (int ks = 0; ks < 2; ++ks) {
                        const int r  = wm * 128 + mq * 64 + i * 16 + l16;
                        const int sl = (ks * 4 + q) ^ rsl;
                        af[i][ks] = *(const short8*)&As[b][r * 64 + sl * 8];
                    }
            }
            short8 bfr[2][2];
#pragma unroll
            for (int i = 0; i < 2; ++i)
#pragma unroll
                for (int ks = 0; ks < 2; ++ks) {
                    const int r  = wn * 64 + nq * 32 + i * 16 + l16;
                    const int sl = (ks * 4 + q) ^ rsl;
                    bfr[i][ks] = *(const short8*)&Bs[b][r * 64 + sl * 8];
                }
            // ---- stage tile T+1 into buf ^b (front-loaded, phases 0/1) ----
            if (T + 1 < NTILE) {
                if (p == 0) {
#pragma unroll
                    for (int j = 0; j < 4; ++j) stageA(b ^ 1, T + 1, j);
                } else if (p == 1) {
#pragma unroll
                    for (int j = 0; j < 4; ++j) stageB(b ^ 1, T + 1, j);
                }
            }
            __builtin_amdgcn_s_barrier();
            asm volatile("s_waitcnt lgkmcnt(0)" ::: "memory");
            __builtin_amdgcn_sched_barrier(0);
            __builtin_amdgcn_s_setprio(1);
#pragma unroll
            for (int ks = 0; ks < 2; ++ks)
#pragma unroll
                for (int i = 0; i < 4; ++i)
#pragma unroll
                    for (int jn = 0; jn < 2; ++jn)
                        acc[mq * 4 + i][nq * 2 + jn] =
                            __builtin_amdgcn_mfma_f32_16x16x32_bf16(
                                af[i][ks], bfr[jn][ks],
                                acc[mq * 4 + i][nq * 2 + jn], 0, 0, 0);
            __builtin_amdgcn_s_setprio(0);
            if (p == 3 && T + 1 < NTILE) {
                // drain tile T+1's stage calls (issued phases 0-1, >=2 phases
                // old) BEFORE the closing barrier -> next tile reads are safe
                asm volatile("s_waitcnt vmcnt(0)" ::: "memory");
                __builtin_amdgcn_sched_barrier(0);
            }
            __builtin_amdgcn_s_barrier();
            __builtin_amdgcn_sched_barrier(0);
        }
    }

    // epilogue: FOLD + RELU, write C
    const float mr = muf * rstdf;
#pragma unroll
    for (int mt = 0; mt < 8; ++mt) {
        const long rowb = m0 + wm * 128 + mt * 16 + q * 4;
#pragma unroll
        for (int nt = 0; nt < 4; ++nt) {
            const long col = n0 + wn * 64 + nt * 16 + l16;
            const float bv = bias[col];
            const float cs = colsum[col];
#pragma unroll
            for (int r = 0; r < 4; ++r) {
                float v = rstdf * acc[mt][nt][r] + bv - mr * cs;
                v = fmaxf(v, 0.0f);
                C[(rowb + r) * (long)N + col] = f2b(v);
            }
        }
    }
}

// ---------------------------------------------------------------------------
// bf16 MFMA GEMM, BMxBN tile, BK in {32,64}, NBUF in {2,3}, 256 thr = 4 waves.
// (unchanged from round 9; used for QKV / out-proj / FF2)
// ---------------------------------------------------------------------------
template <bool RELU, bool RESID, bool STATS, bool FOLD, int BM, int BN, int BK, int NBUF>
__global__ __launch_bounds__(256) void gemm_mfma(const short* __restrict__ A,
                                                 const short* __restrict__ BT,
                                                 const float* __restrict__ bias,
                                                 const float* __restrict__ colsum,
                                                 const short* __restrict__ residB,
                                                 short* __restrict__ C,
                                                 const double* __restrict__ statsIn,
                                                 double* __restrict__ statsOut,
                                                 int M, int N, int K) {
    constexpr int NT   = (BN == 256) ? 4 : ((BM == 128) ? 4 : 2);
    constexpr int KSUB = BK / 32;                    // 32-K sub-steps per tile
    constexpr int RPS  = (BK == 32) ? 64 : 32;       // rows per stage unit (256 lanes)
    constexpr int LPS  = (BM + BN) / RPS;            // loads/lane per staged tile
    __shared__ short As[NBUF][BM * BK];
    __shared__ short Bs[NBUF][BN * BK];
    const int t   = threadIdx.x;
    const int wv  = t >> 6;
    const int l   = t & 63;
    const int q   = l >> 4,  l16 = l & 15;
    const int mbase = (BM == 128) ? (wv >> 1) * 64 : 0;
    const int nbase = (BM == 128) ? (wv & 1) * 64
                    : ((BN == 256) ? wv * 64 : wv * 32);
    const long m0 = (long)blockIdx.x * BM;
    const long n0 = (long)blockIdx.y * BN;

    float muf = 0.f, rstdf = 1.f;
    if (FOLD || RESID) {
        if (statsIn) {
            double mean = statsIn[0] * (1.0 / NTOT);
            double var  = statsIn[1] * (1.0 / NTOT) - mean * mean;
            muf   = (float)mean;
            rstdf = (float)(1.0 / sqrt(var + LN_EPS));
        }
    }

    f32x4 acc[4][NT] = {};

    // staging geometry (see round-5/8 header comments)
    const int srow = (BK == 32) ? (wv * 16 + (l >> 2)) : (wv * 8 + (l >> 3));
    const int kcol = (BK == 32) ? (((l & 3) ^ ((l >> 3) & 3)) * 8)
                                : (((l & 7) ^ ((l >> 3) & 7)) * 8);
    const int wrow = (BK == 32) ? wv * 16 : wv * 8;  // wave's LDS base row

    auto stage = [&](int buf, int k0) {
#pragma unroll
        for (int i = 0; i < BM / RPS; ++i)
            async16(A + (m0 + srow + i * RPS) * (long)K + k0 + kcol,
                    &As[buf][(wrow + i * RPS) * BK + l * 8]);
#pragma unroll
        for (int i = 0; i < BN / RPS; ++i)
            async16(BT + (n0 + srow + i * RPS) * (long)K + k0 + kcol,
                    &Bs[buf][(wrow + i * RPS) * BK + l * 8]);
    };
    auto waitcnt_steady = [&]() {
        if constexpr (LPS == 3)       asm volatile("s_waitcnt vmcnt(3)" ::: "memory");
        else if constexpr (LPS == 4)  asm volatile("s_waitcnt vmcnt(4)" ::: "memory");
        else if constexpr (LPS == 5)  asm volatile("s_waitcnt vmcnt(5)" ::: "memory");
        else if constexpr (LPS == 6)  asm volatile("s_waitcnt vmcnt(6)" ::: "memory");
        else                          asm volatile("s_waitcnt vmcnt(8)" ::: "memory");
    };

    // prologue: up to two tiles in flight
    stage(0, 0);
    if (K > BK) stage(1, BK);
    int cur = 0;
    for (int k0 = 0; k0 < K; k0 += BK) {
        // counted wait: tile[cur] landed; tile cur+1's LPS loads stay in flight
        if (k0 + BK < K) waitcnt_steady();
        else             asm volatile("s_waitcnt vmcnt(0)" ::: "memory");
        __builtin_amdgcn_sched_barrier(0);
        __builtin_amdgcn_s_barrier();          // tile[cur] fully in LDS
        __builtin_amdgcn_sched_barrier(0);

        short8 af[KSUB][4], bfr[KSUB][NT];
#pragma unroll
        for (int ks = 0; ks < KSUB; ++ks) {
            const int slot = (BK == 32) ? (q ^ ((l16 >> 1) & 3))
                                        : ((ks * 4 + q) ^ (l16 & 7));
#pragma unroll
            for (int i = 0; i < 4; ++i)
                af[ks][i] = *(const short8*)&As[cur][(mbase + i * 16 + l16) * BK + slot * 8];
#pragma unroll
            for (int i = 0; i < NT; ++i)
                bfr[ks][i] = *(const short8*)&Bs[cur][(nbase + i * 16 + l16) * BK + slot * 8];
        }

        if constexpr (NBUF == 2) {
            // WAR barrier before re-staging the buffer we just read
            asm volatile("s_waitcnt lgkmcnt(0)" ::: "memory");
            __builtin_amdgcn_sched_barrier(0);
            __builtin_amdgcn_s_barrier();      // all reads done -> WAR-safe
            __builtin_amdgcn_sched_barrier(0);
            if (k0 + 2 * BK < K) stage(cur, k0 + 2 * BK);
        } else {
            // 3-buffer: stage target (cur+2)%3 is neither read nor in-flight
            if (k0 + 2 * BK < K) {
                int sb = cur + 2; if (sb >= 3) sb -= 3;
                stage(sb, k0 + 2 * BK);
            }
        }

        __builtin_amdgcn_s_setprio(1);
#pragma unroll
        for (int ks = 0; ks < KSUB; ++ks)
#pragma unroll
            for (int mt = 0; mt < 4; ++mt)
#pragma unroll
                for (int nt = 0; nt < NT; ++nt)
                    acc[mt][nt] = __builtin_amdgcn_mfma_f32_16x16x32_bf16(
                        af[ks][mt], bfr[ks][nt], acc[mt][nt], 0, 0, 0);
        __builtin_amdgcn_s_setprio(0);

        if constexpr (NBUF == 3) {
            // free drain: my reads of buf[cur] complete before the next step's
            // barrier, which precedes any wave's stage into (cur+2)%3 == cur-1.
            asm volatile("s_waitcnt lgkmcnt(0)" ::: "memory");
            __builtin_amdgcn_sched_barrier(0);
        }

        cur += 1; if (cur >= NBUF) cur = 0;
    }

    const float mr = muf * rstdf;
    float s = 0.f, sq = 0.f;
#pragma unroll
    for (int mt = 0; mt < 4; ++mt) {
        const long rowb = m0 + mbase + mt * 16 + q * 4;
#pragma unroll
        for (int nt = 0; nt < NT; ++nt) {
            const long col = n0 + nbase + nt * 16 + l16;
            const float bv = bias[col];
            const float cs = FOLD ? colsum[col] : 0.f;
#pragma unroll
            for (int r = 0; r < 4; ++r) {
                const long idx = (rowb + r) * (long)N + col;
                float v = acc[mt][nt][r];
                if (FOLD) v = rstdf * v + bv - mr * cs;
                else      v = v + bv;
                if (RESID) v += (b2f(residB[idx]) - muf) * rstdf;
                if (RELU)  v = fmaxf(v, 0.0f);
                if (STATS) { s += v; sq += v * v; }
                C[idx] = f2b(v);
            }
        }
    }
    if (STATS) {
#pragma unroll
        for (int o = 32; o; o >>= 1) {
            s  += __shfl_down(s, o);
            sq += __shfl_down(sq, o);
        }
        __syncthreads();               // all waves past their last LDS reads
        float* sm = (float*)As;        // safe to reuse buf0 as scratch now
        if (l == 0) { sm[wv] = s; sm[4 + wv] = sq; }
        __syncthreads();
        if (t == 0) {
            atomicAdd(&statsOut[0], (double)(sm[0] + sm[1] + sm[2] + sm[3]));
            atomicAdd(&statsOut[1], (double)(sm[4] + sm[5] + sm[6] + sm[7]));
        }
    }
}

// ---------------------------------------------------------------------------
// bf16 MFMA flash attention (unchanged).
// ---------------------------------------------------------------------------
__global__ __launch_bounds__(256) void attn_mfma(const short* __restrict__ qkvb,
                                                 const short* __restrict__ Vtg,
                                                 short* __restrict__ head) {
    const int b  = blockIdx.y;
    const int q0 = blockIdx.x * 64;
    const int t  = threadIdx.x;
    const int w  = t >> 6;
    const int l  = t & 63;
    const int l15 = l & 15, lq = l >> 4;
    const int l7  = l & 7,  l8 = l >> 3;

    __shared__ short Ks[64][72];
    __shared__ short Vs[64][72];
    __shared__ short Ps[4][16][68];

    short8 qf[2];
    {
        const short* qrow = qkvb + (size_t)(b * SS + q0 + w * 16 + l15) * 256;
        qf[0] = *(const short8*)(qrow + lq * 8);
        qf[1] = *(const short8*)(qrow + 32 + lq * 8);
    }

    f32x4 acc[4];
#pragma unroll
    for (int mt = 0; mt < 4; ++mt) acc[mt] = {0.f, 0.f, 0.f, 0.f};
    float m_i = -INFINITY, l_i = 0.f;
    const float sc = 0.0450712500463f;   // log2(e)/32

    short8 kreg[2], vreg[2];
    {
        const short* kb = qkvb + (size_t)(b * SS) * 256 + 64;
        kreg[0] = *(const short8*)(kb + (size_t)(w * 8 + l8) * 256 + l7 * 8);
        kreg[1] = *(const short8*)(kb + (size_t)(32 + w * 8 + l8) * 256 + l7 * 8);
        const short* vb = Vtg + (size_t)b * 64 * SS;
        vreg[0] = *(const short8*)(vb + (size_t)(w * 8 + l8) * SS + l7 * 8);
        vreg[1] = *(const short8*)(vb + (size_t)(32 + w * 8 + l8) * SS + l7 * 8);
    }

    for (int kt = 0; kt < SS / 64; ++kt) {
        __syncthreads();
        *(short8*)&Ks[w * 8 + l8][l7 * 8]      = kreg[0];
        *(short8*)&Ks[32 + w * 8 + l8][l7 * 8] = kreg[1];
        *(short8*)&Vs[w * 8 + l8][l7 * 8]      = vreg[0];
        *(short8*)&Vs[32 + w * 8 + l8][l7 * 8] = vreg[1];
        if (kt + 1 < SS / 64) {
            const short* kb = qkvb + (size_t)(b * SS + (kt + 1) * 64) * 256 + 64;
            kreg[0] = *(const short8*)(kb + (size_t)(w * 8 + l8) * 256 + l7 * 8);
            kreg[1] = *(const short8*)(kb + (size_t)(32 + w * 8 + l8) * 256 + l7 * 8);
            const short* vb = Vtg + (size_t)b * 64 * SS + (kt + 1) * 64;
            vreg[0] = *(const short8*)(vb + (size_t)(w * 8 + l8) * SS + l7 * 8);
            vreg[1] = *(const short8*)(vb + (size_t)(32 + w * 8 + l8) * SS + l7 * 8);
        }
        __syncthreads();

        f32x4 st[4];
#pragma unroll
        for (int mt = 0; mt < 4; ++mt) st[mt] = {0.f, 0.f, 0.f, 0.f};
#pragma unroll
        for (int kc = 0; kc < 2; ++kc)
#pragma unroll
            for (int mt = 0; mt < 4; ++mt) {
                short8 kf = *(const short8*)&Ks[mt * 16 + l15][kc * 32 + lq * 8];
                st[mt] = __builtin_amdgcn_mfma_f32_16x16x32_bf16(kf, qf[kc], st[mt], 0, 0, 0);
            }
        float mx = m_i;
#pragma unroll
        for (int mt = 0; mt < 4; ++mt)
#pragma unroll
            for (int r = 0; r < 4; ++r) {
                st[mt][r] *= sc;
                mx = fmaxf(mx, st[mt][r]);
            }
        mx = fmaxf(mx, __shfl_xor(mx, 16));
        mx = fmaxf(mx, __shfl_xor(mx, 32));
        float alpha = exp2f(m_i - mx);
        float rs = 0.f;
#pragma unroll
        for (int mt = 0; mt < 4; ++mt) {
            s16x4 pk;
#pragma unroll
            for (int r = 0; r < 4; ++r) {
                float p = exp2f(st[mt][r] - mx);
                rs += p;
                pk[r] = f2b(p);
            }
            *(s16x4*)&Ps[w][l15][mt * 16 + lq * 4] = pk;
        }
        rs += __shfl_xor(rs, 16);
        rs += __shfl_xor(rs, 32);
        l_i = l_i * alpha + rs;
        m_i = mx;
#pragma unroll
        for (int mt = 0; mt < 4; ++mt)
#pragma unroll
            for (int r = 0; r < 4; ++r) acc[mt][r] *= alpha;

#pragma unroll
        for (int kc = 0; kc < 2; ++kc) {
            s16x4 p0 = *(const s16x4*)&Ps[w][l15][kc * 32 + lq * 8];
            s16x4 p1 = *(const s16x4*)&Ps[w][l15][kc * 32 + lq * 8 + 4];
            short8 pf = __builtin_shufflevector(p0, p1, 0, 1, 2, 3, 4, 5, 6, 7);
#pragma unroll
            for (int mt = 0; mt < 4; ++mt) {
                short8 vf = *(const short8*)&Vs[mt * 16 + l15][kc * 32 + lq * 8];
                acc[mt] = __builtin_amdgcn_mfma_f32_16x16x32_bf16(vf, pf, acc[mt], 0, 0, 0);
            }
        }
    }
    float inv = 1.0f / l_i;
    short* out = head + (size_t)(b * SS + q0 + w * 16 + l15) * 64;
#pragma unroll
    for (int mt = 0; mt < 4; ++mt) {
        s16x4 o;
#pragma unroll
        for (int r = 0; r < 4; ++r) o[r] = f2b(acc[mt][r] * inv);
        *(s16x4*)&out[mt * 16 + lq * 4] = o;
    }
}

// ---------------------------------------------------------------------------
// Final LN2 normalize: d_out fp32 = (b2f(T1) - mu)*rstd
// ---------------------------------------------------------------------------
__global__ __launch_bounds__(256) void lnfinal_kernel(const short* __restrict__ y,
                                                      float* __restrict__ out,
                                                      const double* __restrict__ red,
                                                      int n) {
    double mean = red[0] / n;
    double var  = red[1] / n - mean * mean;
    float mu   = (float)mean;
    float rstd = (float)(1.0 / sqrt(var + LN_EPS));
    for (int i = blockIdx.x * blockDim.x + threadIdx.x; i < n;
         i += gridDim.x * blockDim.x)
        out[i] = (b2f(y[i]) - mu) * rstd;
}

// ---------------------------------------------------------------------------
extern "C" void kernel_launch(void* const* d_in, const int* in_sizes, int n_in,
                              void* d_out, int out_size, void* d_ws, size_t ws_size,
                              hipStream_t stream) {
    const int*   ids = (const int*)d_in[0];
    const float* emb = (const float*)d_in[1];
    const float* Wq  = (const float*)d_in[2];
    const float* bq  = (const float*)d_in[3];
    const float* Wk  = (const float*)d_in[4];
    const float* bk  = (const float*)d_in[5];
    const float* Wv  = (const float*)d_in[6];
    const float* bv  = (const float*)d_in[7];
    const float* Wo  = (const float*)d_in[8];
    const float* bo  = (const float*)d_in[9];
    const float* W1  = (const float*)d_in[10];
    const float* b1  = (const float*)d_in[11];
    const float* W2  = (const float*)d_in[12];
    const float* b2  = (const float*)d_in[13];

    float* xout = (float*)d_out;                     // final output only
    char* w = (char*)d_ws;

    // Buffers (bf16 unless noted):
    //   hch  [16384][2048] (full) or [8192][2048] (chunked) -- FF hidden
    //   qkvb [16384][256], Vtg [8][64][2048], head [16384][64]  (alias in hch)
    //   T1   trunk y (rep input / FF2 output), T2 trunk z (outproj output)
    const bool big = ws_size >= (size_t)105195712 + 256;

    short *qkvb, *Vtg, *head, *T1, *T2, *hch, *WqkvT, *WoST, *W1T, *W2T;
    float *bqkv, *csq, *csw1; double* red;

    if (big) {
        hch   = (short*)(w + 0);                     // 64 MB
        qkvb  = (short*)(w + 0);                     //  8 MB (alias)
        Vtg   = (short*)(w + 8388608);               //  2 MB (alias)
        head  = (short*)(w + 10485760);              //  2 MB (alias)
        T1    = (short*)(w + 67108864);              // 16 MB
        T2    = (short*)(w + 83886080);              // 16 MB
        WqkvT = (short*)(w + 100663296);
        bqkv  = (float*)(w + 100925440);
        csq   = (float*)(w + 100926464);
        WoST  = (short*)(w + 100927488);
        W1T   = (short*)(w + 100993024);
        csw1  = (float*)(w + 103090176);
        W2T   = (short*)(w + 103098368);
        red   = (double*)(w + 105195520);
    } else {
        hch   = (short*)(w + 0);                     // 32 MB (M=8192 chunks)
        qkvb  = (short*)(w + 0);
        Vtg   = (short*)(w + 8388608);
        head  = (short*)(w + 10485760);
        T1    = (short*)(w + 33554432);
        T2    = (short*)(w + 50331648);
        WqkvT = (short*)(w + 67108864);
        bqkv  = (float*)(w + 67371008);
        csq   = (float*)(w + 67372032);
        WoST  = (short*)(w + 67373056);
        W1T   = (short*)(w + 67438592);
        csw1  = (float*)(w + 69535744);
        W2T   = (short*)(w + 69543936);
        red   = (double*)(w + 71641088);
    }

    // ---- setup (once per launch) ----
    packqkvT_kernel<<<(256 * 512 + 255) / 256, 256, 0, stream>>>(Wq, Wk, Wv, bq, bk, bv, WqkvT, bqkv);
    wosumT_kernel<<<(512 * 64 + 255) / 256, 256, 0, stream>>>(Wo, WoST);
    transpose_b16<<<dim3(2048 / 32, 512 / 32), 256, 0, stream>>>(W1, W1T, 512, 2048);
    transpose_b16<<<dim3(512 / 32, 2048 / 32), 256, 0, stream>>>(W2, W2T, 2048, 512);
    colsum_kernel<<<9, 256, 0, stream>>>(WqkvT, W1T, csq, csw1);
    embed_kernel<<<NTOT / 256, 256, 0, stream>>>(ids, emb, T1, red);

    for (int rep = 0; rep < 6; ++rep) {
        const double* sprev = rep ? red + 4 * (rep - 1) + 2 : nullptr;  // LN2 stats of prev rep
        double* red1 = red + 4 * rep;        // LN1 stats (over z = outproj out)
        double* red2 = red + 4 * rep + 2;    // LN2 stats (over y' = FF2 out)

        // QKV: LN2-folded  qkvb = LN(T1) @ Wqkv + bqkv   [16384][256]
        gemm_mfma<false, false, false, true, 64, 128, 64, 2><<<dim3(256, 2), 256, 0, stream>>>(
            T1, WqkvT, bqkv, csq, nullptr, qkvb, sprev, nullptr, ROWS, 256, DM);
        // V transpose
        vtrans_kernel<<<dim3(SS / 32, 2, BB), 256, 0, stream>>>(qkvb, Vtg);
        // flash attention -> head
        attn_mfma<<<dim3(SS / 64, BB), 256, 0, stream>>>(qkvb, Vtg, head);
        // out-proj: T2 = head @ WoS + bo + LN(T1); stats -> red1
        gemm_mfma<false, true, true, false, 64, 128, 64, 2><<<dim3(256, 4), 256, 0, stream>>>(
            head, WoST, bo, nullptr, T1, T2, sprev, red1, ROWS, DM, DK);
        // FF (LN1 folded into FF1 via 8-phase 256^2 kernel; FF2 3buf)
        if (big) {
            gemm_ff1_8p<<<dim3(64, 8), 512, 0, stream>>>(
                T2, W1T, b1, csw1, hch, red1, ROWS, DFF);
            gemm_mfma<false, true, true, false, 64, 256, 32, 3><<<dim3(256, 2), 256, 0, stream>>>(
                hch, W2T, b2, nullptr, T2, T1, red1, red2, ROWS, DM, DFF);
        } else {
            for (int c = 0; c < 2; ++c) {
                const size_t off = (size_t)c * 8192 * DM;
                gemm_ff1_8p<<<dim3(32, 8), 512, 0, stream>>>(
                    T2 + off, W1T, b1, csw1, hch, red1, 8192, DFF);
                gemm_mfma<false, true, true, false, 64, 256, 32, 3><<<dim3(128, 2), 256, 0, stream>>>(
                    hch, W2T, b2, nullptr, T2 + off, T1 + off, red1, red2, 8192, DM, DFF);
            }
        }
    }
    // final LN2 normalize -> fp32 output
    lnfinal_kernel<<<4096, 256, 0, stream>>>(T1, xout, red + 4 * 5 + 2, NTOT);
}

// Round 12
// 1199.998 us; speedup vs baseline: 1.1029x; 1.0769x over previous
//
#include <hip/hip_runtime.h>
#include <math.h>

// Problem constants
#define BB 8
#define SS 2048
#define DM 512
#define DK 64
#define DFF 2048
#define ROWS (BB*SS)          // 16384
#define NTOT (ROWS*DM)        // 8388608
#define LN_EPS 1e-5
#define PAD_IDX 0

typedef __attribute__((ext_vector_type(8))) short short8;
typedef __attribute__((ext_vector_type(4))) short s16x4;
typedef __attribute__((ext_vector_type(4))) float f32x4;

__device__ __forceinline__ short f2b(float f) {        // fp32 -> bf16 (RNE)
    unsigned u = __float_as_uint(f);
    unsigned r = (u + 0x7fffu + ((u >> 16) & 1u)) >> 16;
    return (short)r;
}
__device__ __forceinline__ float b2f(short s) {        // bf16 -> fp32
    return __uint_as_float(((unsigned)(unsigned short)s) << 16);
}

// ---------------------------------------------------------------------------
// Embedding + positional encoding -> trunk T1 (bf16); zero LN stat slots
// ---------------------------------------------------------------------------
__global__ __launch_bounds__(256) void embed_kernel(const int* __restrict__ ids,
                                                    const float* __restrict__ emb,
                                                    short* __restrict__ T1,
                                                    double* __restrict__ red) {
    int idx = blockIdx.x * 256 + threadIdx.x;
    if (idx < 24) red[idx] = 0.0;              // 12 LN slots x (sum,sumsq)
    if (idx >= NTOT) return;
    int d   = idx & (DM - 1);
    int row = idx >> 9;
    int s   = row & (SS - 1);
    int id  = ids[row];
    float e = (id != PAD_IDX) ? emb[(size_t)id * DM + d] : 0.0f;
    float ex  = 2.0f * (float)d / 512.0f;
    float div = powf(10000.0f, ex);
    float arg = (float)s / div;
    float pe  = (d & 1) ? cosf(arg) : sinf(arg);
    T1[idx] = f2b(e + pe);
}

// ---------------------------------------------------------------------------
// Weight packing: WqkvT bf16 [256][512] (rows 192..255 zero) + bqkv fp32[256]
// ---------------------------------------------------------------------------
__global__ __launch_bounds__(256) void packqkvT_kernel(const float* __restrict__ Wq,
                                                       const float* __restrict__ Wk,
                                                       const float* __restrict__ Wv,
                                                       const float* __restrict__ bq,
                                                       const float* __restrict__ bk,
                                                       const float* __restrict__ bv,
                                                       short* __restrict__ WqkvT,
                                                       float* __restrict__ bqkv) {
    int i = blockIdx.x * 256 + threadIdx.x;
    if (i < 256 * 512) {
        int n = i >> 9, k = i & 511;
        float v = (n < 64)  ? Wq[k * 64 + n]
                : (n < 128) ? Wk[k * 64 + (n - 64)]
                : (n < 192) ? Wv[k * 64 + (n - 128)] : 0.0f;
        WqkvT[i] = f2b(v);
    }
    if (i < 256)
        bqkv[i] = (i < 64) ? bq[i] : (i < 128) ? bk[i - 64] : (i < 192) ? bv[i - 128] : 0.0f;
}

// WoST bf16 [512][64]: WoST[e][k] = sum_h Wo[h*64+k][e]
__global__ __launch_bounds__(256) void wosumT_kernel(const float* __restrict__ Wo,
                                                     short* __restrict__ WoST) {
    int i = blockIdx.x * 256 + threadIdx.x;
    if (i >= 512 * 64) return;
    int e = i >> 6, k = i & 63;
    float s = 0.f;
#pragma unroll
    for (int h = 0; h < 8; ++h) s += Wo[(size_t)(h * 64 + k) * 512 + e];
    WoST[i] = f2b(s);
}

// Tiled transpose fp32[R][C] -> bf16[C][R]
__global__ __launch_bounds__(256) void transpose_b16(const float* __restrict__ in,
                                                     short* __restrict__ out,
                                                     int R, int C) {
    __shared__ float tile[32][33];
    int bx = blockIdx.x * 32;
    int by = blockIdx.y * 32;
    int tx = threadIdx.x & 31, ty = threadIdx.x >> 5;
#pragma unroll
    for (int i = 0; i < 32; i += 8)
        tile[ty + i][tx] = in[(size_t)(by + ty + i) * C + bx + tx];
    __syncthreads();
#pragma unroll
    for (int i = 0; i < 32; i += 8)
        out[(size_t)(bx + ty + i) * R + by + tx] = f2b(tile[tx][ty + i]);
}

// Column sums of bf16 weights (for LN folding):
// csq[n<256] = sum_k WqkvT[n][k]; csw1[n<2048] = sum_k W1T[n][k]
__global__ __launch_bounds__(256) void colsum_kernel(const short* __restrict__ WqkvT,
                                                     const short* __restrict__ W1T,
                                                     float* __restrict__ csq,
                                                     float* __restrict__ csw1) {
    int i = blockIdx.x * 256 + threadIdx.x;
    if (i < 256) {
        const short* p = WqkvT + (size_t)i * 512;
        float s = 0.f;
        for (int k = 0; k < 512; ++k) s += b2f(p[k]);
        csq[i] = s;
    } else if (i < 2304) {
        int n = i - 256;
        const short* p = W1T + (size_t)n * 512;
        float s = 0.f;
        for (int k = 0; k < 512; ++k) s += b2f(p[k]);
        csw1[n] = s;
    }
}

// V slice of qkvb [16384][256] -> Vtg bf16 [8][64][2048]
__global__ __launch_bounds__(256) void vtrans_kernel(const short* __restrict__ qkvb,
                                                     short* __restrict__ Vtg) {
    __shared__ short tile[32][40];
    int sx = blockIdx.x * 32;
    int dy = blockIdx.y * 32;
    int b  = blockIdx.z;
    int tx = threadIdx.x & 31, ty = threadIdx.x >> 5;
#pragma unroll
    for (int i = 0; i < 32; i += 8)
        tile[ty + i][tx] = qkvb[(size_t)(b * SS + sx + ty + i) * 256 + 128 + dy + tx];
    __syncthreads();
#pragma unroll
    for (int i = 0; i < 32; i += 8)
        Vtg[(size_t)(b * 64 + dy + ty + i) * SS + sx + tx] = tile[tx][ty + i];
}

__device__ __forceinline__ void async16(const void* g, void* l) {
    __builtin_amdgcn_global_load_lds(
        (const __attribute__((address_space(1))) void*)g,
        (__attribute__((address_space(3))) void*)l, 16, 0, 0);
}

// ---------------------------------------------------------------------------
// FF1 8-phase 256x256 kernel (round-10, kept: not measurably worse, <66us).
// ---------------------------------------------------------------------------
__global__ __launch_bounds__(512) void gemm_ff1_8p(const short* __restrict__ A,
                                                   const short* __restrict__ BT,
                                                   const float* __restrict__ bias,
                                                   const float* __restrict__ colsum,
                                                   short* __restrict__ C,
                                                   const double* __restrict__ statsIn,
                                                   int M, int N) {
    constexpr int K = 512;
    constexpr int NTILE = K / 64;            // 8 K-tiles
    __shared__ short As[2][256 * 64];
    __shared__ short Bs[2][256 * 64];
    const int t   = threadIdx.x;
    const int wid = t >> 6;
    const int l   = t & 63;
    const int q   = l >> 4, l16 = l & 15;
    const int wm  = wid >> 2, wn = wid & 3;  // 2 x 4 wave grid
    const long m0 = (long)blockIdx.x * 256;
    const long n0 = (long)blockIdx.y * 256;

    float muf = 0.f, rstdf = 1.f;
    if (statsIn) {
        double mean = statsIn[0] * (1.0 / NTOT);
        double var  = statsIn[1] * (1.0 / NTOT) - mean * mean;
        muf   = (float)mean;
        rstdf = (float)(1.0 / sqrt(var + LN_EPS));
    }

    f32x4 acc[8][4] = {};

    const short* Ab = A  + m0 * K;
    const short* Bb = BT + n0 * K;
    const int srow = t >> 3;                          // 0..63 within a quarter
    const int kcol = ((t & 7) ^ ((t >> 3) & 7)) * 8;  // pre-swizzled src chunk
    const int rsl  = l16 & 7;                         // read-slot xor term

    // stage quarter j (64 rows) of K-tile T into buf b
    auto stageA = [&](int b, int T, int j) {
        async16(Ab + (long)(j * 64 + srow) * K + T * 64 + kcol,
                &As[b][j * 64 * 64 + t * 8]);
    };
    auto stageB = [&](int b, int T, int j) {
        async16(Bb + (long)(j * 64 + srow) * K + T * 64 + kcol,
                &Bs[b][j * 64 * 64 + t * 8]);
    };

    // prologue: tile 0 -> buf 0, fully drained
#pragma unroll
    for (int j = 0; j < 4; ++j) { stageA(0, 0, j); stageB(0, 0, j); }
    asm volatile("s_waitcnt vmcnt(0)" ::: "memory");
    __builtin_amdgcn_sched_barrier(0);
    __builtin_amdgcn_s_barrier();
    __builtin_amdgcn_sched_barrier(0);

    short8 af[4][2];                 // A frags persist across the 2 nq phases
    for (int T = 0; T < NTILE; ++T) {
        const int b = T & 1;
#pragma unroll
        for (int p = 0; p < 4; ++p) {
            const int mq = p >> 1, nq = p & 1;
            // ---- ds reads for this phase (buf b is stable this tile) ----
            if (nq == 0) {
#pragma unroll
                for (int i = 0; i < 4; ++i)
#pragma unroll
                    for (int ks = 0; ks < 2; ++ks) {
                        const int r  = wm * 128 + mq * 64 + i * 16 + l16;
                        const int sl = (ks * 4 + q) ^ rsl;
                        af[i][ks] = *(const short8*)&As[b][r * 64 + sl * 8];
                    }
            }
            short8 bfr[2][2];
#pragma unroll
            for (int i = 0; i < 2; ++i)
#pragma unroll
                for (int ks = 0; ks < 2; ++ks) {
                    const int r  = wn * 64 + nq * 32 + i * 16 + l16;
                    const int sl = (ks * 4 + q) ^ rsl;
                    bfr[i][ks] = *(const short8*)&Bs[b][r * 64 + sl * 8];
                }
            // ---- stage tile T+1 into buf ^b (front-loaded, phases 0/1) ----
            if (T + 1 < NTILE) {
                if (p == 0) {
#pragma unroll
                    for (int j = 0; j < 4; ++j) stageA(b ^ 1, T + 1, j);
                } else if (p == 1) {
#pragma unroll
                    for (int j = 0; j < 4; ++j) stageB(b ^ 1, T + 1, j);
                }
            }
            __builtin_amdgcn_s_barrier();
            asm volatile("s_waitcnt lgkmcnt(0)" ::: "memory");
            __builtin_amdgcn_sched_barrier(0);
            __builtin_amdgcn_s_setprio(1);
#pragma unroll
            for (int ks = 0; ks < 2; ++ks)
#pragma unroll
                for (int i = 0; i < 4; ++i)
#pragma unroll
                    for (int jn = 0; jn < 2; ++jn)
                        acc[mq * 4 + i][nq * 2 + jn] =
                            __builtin_amdgcn_mfma_f32_16x16x32_bf16(
                                af[i][ks], bfr[jn][ks],
                                acc[mq * 4 + i][nq * 2 + jn], 0, 0, 0);
            __builtin_amdgcn_s_setprio(0);
            if (p == 3 && T + 1 < NTILE) {
                asm volatile("s_waitcnt vmcnt(0)" ::: "memory");
                __builtin_amdgcn_sched_barrier(0);
            }
            __builtin_amdgcn_s_barrier();
            __builtin_amdgcn_sched_barrier(0);
        }
    }

    // epilogue: FOLD + RELU, write C
    const float mr = muf * rstdf;
#pragma unroll
    for (int mt = 0; mt < 8; ++mt) {
        const long rowb = m0 + wm * 128 + mt * 16 + q * 4;
#pragma unroll
        for (int nt = 0; nt < 4; ++nt) {
            const long col = n0 + wn * 64 + nt * 16 + l16;
            const float bv = bias[col];
            const float cs = colsum[col];
#pragma unroll
            for (int r = 0; r < 4; ++r) {
                float v = rstdf * acc[mt][nt][r] + bv - mr * cs;
                v = fmaxf(v, 0.0f);
                C[(rowb + r) * (long)N + col] = f2b(v);
            }
        }
    }
}

// ---------------------------------------------------------------------------
// FF2 8-wave kernel (round-11 experiment, resubmitted after infra failure).
// 512 thr = 8 waves (2m x 4n), block tile 128x256, per-wave 64x64, BK=32,
// NBUF=3 single-barrier rotation. Grid (M/128, 2) = 256 blocks = 1/CU,
// 8 waves/CU (same wave count as round-9 FF2, half the barrier-steps/CU,
// 40% less stage traffic).
// Stage: thread t -> row t>>2, dst byte = base + 16*t (linear); source chunk
// pre-swizzled ((t&3)^((t>>3)&3))*8. Read slot q^((l16>>1)&3). LPS=3 ->
// steady vmcnt(3). Fixed flags: RESID=1 (LN1(T2) via statsIn), STATS=1.
// ---------------------------------------------------------------------------
__global__ __launch_bounds__(512) void gemm_ff2_8w(const short* __restrict__ A,
                                                   const short* __restrict__ BT,
                                                   const float* __restrict__ bias,
                                                   const short* __restrict__ residB,
                                                   short* __restrict__ C,
                                                   const double* __restrict__ statsIn,
                                                   double* __restrict__ statsOut,
                                                   int M, int N, int K) {
    __shared__ short As[3][128 * 32];
    __shared__ short Bs[3][256 * 32];
    const int t   = threadIdx.x;
    const int wid = t >> 6;
    const int l   = t & 63;
    const int q   = l >> 4, l16 = l & 15;
    const int wm  = wid >> 2, wn = wid & 3;     // 2 x 4 wave grid
    const int mbase = wm * 64, nbase = wn * 64;
    const long m0 = (long)blockIdx.x * 128;
    const long n0 = (long)blockIdx.y * 256;

    float muf = 0.f, rstdf = 1.f;
    if (statsIn) {
        double mean = statsIn[0] * (1.0 / NTOT);
        double var  = statsIn[1] * (1.0 / NTOT) - mean * mean;
        muf   = (float)mean;
        rstdf = (float)(1.0 / sqrt(var + LN_EPS));
    }

    f32x4 acc[4][4] = {};

    const int srow = t >> 2;                          // 0..127
    const int kcol = (((t & 3) ^ ((t >> 3) & 3)) * 8);// pre-swizzled src chunk
    const int csw  = (l16 >> 1) & 3;                  // read-slot xor

    auto stage = [&](int buf, int k0) {
        async16(A + (m0 + srow) * (long)K + k0 + kcol,
                &As[buf][srow * 32 + (t & 3) * 8]);
#pragma unroll
        for (int i = 0; i < 2; ++i)
            async16(BT + (n0 + i * 128 + srow) * (long)K + k0 + kcol,
                    &Bs[buf][(i * 128 + srow) * 32 + (t & 3) * 8]);
    };

    // prologue: two tiles in flight
    stage(0, 0);
    stage(1, 32);
    int cur = 0;
    for (int k0 = 0; k0 < K; k0 += 32) {
        if (k0 + 32 < K) asm volatile("s_waitcnt vmcnt(3)" ::: "memory");
        else             asm volatile("s_waitcnt vmcnt(0)" ::: "memory");
        __builtin_amdgcn_sched_barrier(0);
        __builtin_amdgcn_s_barrier();          // tile[cur] fully in LDS
        __builtin_amdgcn_sched_barrier(0);

        short8 af[4], bfr[4];
        const int slot = q ^ csw;
#pragma unroll
        for (int i = 0; i < 4; ++i)
            af[i] = *(const short8*)&As[cur][(mbase + i * 16 + l16) * 32 + slot * 8];
#pragma unroll
        for (int i = 0; i < 4; ++i)
            bfr[i] = *(const short8*)&Bs[cur][(nbase + i * 16 + l16) * 32 + slot * 8];

        if (k0 + 64 < K) {                     // stage tile i+2 -> buf (cur+2)%3
            int sb = cur + 2; if (sb >= 3) sb -= 3;
            stage(sb, k0 + 64);
        }

        __builtin_amdgcn_s_setprio(1);
#pragma unroll
        for (int mt = 0; mt < 4; ++mt)
#pragma unroll
            for (int nt = 0; nt < 4; ++nt)
                acc[mt][nt] = __builtin_amdgcn_mfma_f32_16x16x32_bf16(
                    af[mt], bfr[nt], acc[mt][nt], 0, 0, 0);
        __builtin_amdgcn_s_setprio(0);

        // free drain: my reads of buf[cur] complete before the next step's
        // barrier, which precedes any wave's stage into buf cur.
        asm volatile("s_waitcnt lgkmcnt(0)" ::: "memory");
        __builtin_amdgcn_sched_barrier(0);

        cur += 1; if (cur >= 3) cur = 0;
    }

    float s = 0.f, sq = 0.f;
#pragma unroll
    for (int mt = 0; mt < 4; ++mt) {
        const long rowb = m0 + mbase + mt * 16 + q * 4;
#pragma unroll
        for (int nt = 0; nt < 4; ++nt) {
            const long col = n0 + nbase + nt * 16 + l16;
            const float bv = bias[col];
#pragma unroll
            for (int r = 0; r < 4; ++r) {
                const long idx = (rowb + r) * (long)N + col;
                float v = acc[mt][nt][r] + bv;
                v += (b2f(residB[idx]) - muf) * rstdf;
                s += v; sq += v * v;
                C[idx] = f2b(v);
            }
        }
    }
#pragma unroll
    for (int o = 32; o; o >>= 1) {
        s  += __shfl_down(s, o);
        sq += __shfl_down(sq, o);
    }
    __syncthreads();               // all waves past their last LDS reads
    float* sm = (float*)As;        // safe to reuse as scratch now
    if (l == 0) { sm[wid] = s; sm[8 + wid] = sq; }
    __syncthreads();
    if (t == 0) {
        float ts = 0.f, tq = 0.f;
#pragma unroll
        for (int i = 0; i < 8; ++i) { ts += sm[i]; tq += sm[8 + i]; }
        atomicAdd(&statsOut[0], (double)ts);
        atomicAdd(&statsOut[1], (double)tq);
    }
}

// ---------------------------------------------------------------------------
// bf16 MFMA GEMM, BMxBN tile, BK in {32,64}, NBUF in {2,3}, 256 thr = 4 waves.
// (unchanged; used for QKV / out-proj / small-path FF2)
// ---------------------------------------------------------------------------
template <bool RELU, bool RESID, bool STATS, bool FOLD, int BM, int BN, int BK, int NBUF>
__global__ __launch_bounds__(256) void gemm_mfma(const short* __restrict__ A,
                                                 const short* __restrict__ BT,
                                                 const float* __restrict__ bias,
                                                 const float* __restrict__ colsum,
                                                 const short* __restrict__ residB,
                                                 short* __restrict__ C,
                                                 const double* __restrict__ statsIn,
                                                 double* __restrict__ statsOut,
                                                 int M, int N, int K) {
    constexpr int NT   = (BN == 256) ? 4 : ((BM == 128) ? 4 : 2);
    constexpr int KSUB = BK / 32;                    // 32-K sub-steps per tile
    constexpr int RPS  = (BK == 32) ? 64 : 32;       // rows per stage unit (256 lanes)
    constexpr int LPS  = (BM + BN) / RPS;            // loads/lane per staged tile
    __shared__ short As[NBUF][BM * BK];
    __shared__ short Bs[NBUF][BN * BK];
    const int t   = threadIdx.x;
    const int wv  = t >> 6;
    const int l   = t & 63;
    const int q   = l >> 4,  l16 = l & 15;
    const int mbase = (BM == 128) ? (wv >> 1) * 64 : 0;
    const int nbase = (BM == 128) ? (wv & 1) * 64
                    : ((BN == 256) ? wv * 64 : wv * 32);
    const long m0 = (long)blockIdx.x * BM;
    const long n0 = (long)blockIdx.y * BN;

    float muf = 0.f, rstdf = 1.f;
    if (FOLD || RESID) {
        if (statsIn) {
            double mean = statsIn[0] * (1.0 / NTOT);
            double var  = statsIn[1] * (1.0 / NTOT) - mean * mean;
            muf   = (float)mean;
            rstdf = (float)(1.0 / sqrt(var + LN_EPS));
        }
    }

    f32x4 acc[4][NT] = {};

    // staging geometry (see round-5/8 header comments)
    const int srow = (BK == 32) ? (wv * 16 + (l >> 2)) : (wv * 8 + (l >> 3));
    const int kcol = (BK == 32) ? (((l & 3) ^ ((l >> 3) & 3)) * 8)
                                : (((l & 7) ^ ((l >> 3) & 7)) * 8);
    const int wrow = (BK == 32) ? wv * 16 : wv * 8;  // wave's LDS base row

    auto stage = [&](int buf, int k0) {
#pragma unroll
        for (int i = 0; i < BM / RPS; ++i)
            async16(A + (m0 + srow + i * RPS) * (long)K + k0 + kcol,
                    &As[buf][(wrow + i * RPS) * BK + l * 8]);
#pragma unroll
        for (int i = 0; i < BN / RPS; ++i)
            async16(BT + (n0 + srow + i * RPS) * (long)K + k0 + kcol,
                    &Bs[buf][(wrow + i * RPS) * BK + l * 8]);
    };
    auto waitcnt_steady = [&]() {
        if constexpr (LPS == 3)       asm volatile("s_waitcnt vmcnt(3)" ::: "memory");
        else if constexpr (LPS == 4)  asm volatile("s_waitcnt vmcnt(4)" ::: "memory");
        else if constexpr (LPS == 5)  asm volatile("s_waitcnt vmcnt(5)" ::: "memory");
        else if constexpr (LPS == 6)  asm volatile("s_waitcnt vmcnt(6)" ::: "memory");
        else                          asm volatile("s_waitcnt vmcnt(8)" ::: "memory");
    };

    // prologue: up to two tiles in flight
    stage(0, 0);
    if (K > BK) stage(1, BK);
    int cur = 0;
    for (int k0 = 0; k0 < K; k0 += BK) {
        // counted wait: tile[cur] landed; tile cur+1's LPS loads stay in flight
        if (k0 + BK < K) waitcnt_steady();
        else             asm volatile("s_waitcnt vmcnt(0)" ::: "memory");
        __builtin_amdgcn_sched_barrier(0);
        __builtin_amdgcn_s_barrier();          // tile[cur] fully in LDS
        __builtin_amdgcn_sched_barrier(0);

        short8 af[KSUB][4], bfr[KSUB][NT];
#pragma unroll
        for (int ks = 0; ks < KSUB; ++ks) {
            const int slot = (BK == 32) ? (q ^ ((l16 >> 1) & 3))
                                        : ((ks * 4 + q) ^ (l16 & 7));
#pragma unroll
            for (int i = 0; i < 4; ++i)
                af[ks][i] = *(const short8*)&As[cur][(mbase + i * 16 + l16) * BK + slot * 8];
#pragma unroll
            for (int i = 0; i < NT; ++i)
                bfr[ks][i] = *(const short8*)&Bs[cur][(nbase + i * 16 + l16) * BK + slot * 8];
        }

        if constexpr (NBUF == 2) {
            // WAR barrier before re-staging the buffer we just read
            asm volatile("s_waitcnt lgkmcnt(0)" ::: "memory");
            __builtin_amdgcn_sched_barrier(0);
            __builtin_amdgcn_s_barrier();      // all reads done -> WAR-safe
            __builtin_amdgcn_sched_barrier(0);
            if (k0 + 2 * BK < K) stage(cur, k0 + 2 * BK);
        } else {
            // 3-buffer: stage target (cur+2)%3 is neither read nor in-flight
            if (k0 + 2 * BK < K) {
                int sb = cur + 2; if (sb >= 3) sb -= 3;
                stage(sb, k0 + 2 * BK);
            }
        }

        __builtin_amdgcn_s_setprio(1);
#pragma unroll
        for (int ks = 0; ks < KSUB; ++ks)
#pragma unroll
            for (int mt = 0; mt < 4; ++mt)
#pragma unroll
                for (int nt = 0; nt < NT; ++nt)
                    acc[mt][nt] = __builtin_amdgcn_mfma_f32_16x16x32_bf16(
                        af[ks][mt], bfr[ks][nt], acc[mt][nt], 0, 0, 0);
        __builtin_amdgcn_s_setprio(0);

        if constexpr (NBUF == 3) {
            // free drain: my reads of buf[cur] complete before the next step's
            // barrier, which precedes any wave's stage into (cur+2)%3 == cur-1.
            asm volatile("s_waitcnt lgkmcnt(0)" ::: "memory");
            __builtin_amdgcn_sched_barrier(0);
        }

        cur += 1; if (cur >= NBUF) cur = 0;
    }

    const float mr = muf * rstdf;
    float s = 0.f, sq = 0.f;
#pragma unroll
    for (int mt = 0; mt < 4; ++mt) {
        const long rowb = m0 + mbase + mt * 16 + q * 4;
#pragma unroll
        for (int nt = 0; nt < NT; ++nt) {
            const long col = n0 + nbase + nt * 16 + l16;
            const float bv = bias[col];
            const float cs = FOLD ? colsum[col] : 0.f;
#pragma unroll
            for (int r = 0; r < 4; ++r) {
                const long idx = (rowb + r) * (long)N + col;
                float v = acc[mt][nt][r];
                if (FOLD) v = rstdf * v + bv - mr * cs;
                else      v = v + bv;
                if (RESID) v += (b2f(residB[idx]) - muf) * rstdf;
                if (RELU)  v = fmaxf(v, 0.0f);
                if (STATS) { s += v; sq += v * v; }
                C[idx] = f2b(v);
            }
        }
    }
    if (STATS) {
#pragma unroll
        for (int o = 32; o; o >>= 1) {
            s  += __shfl_down(s, o);
            sq += __shfl_down(sq, o);
        }
        __syncthreads();               // all waves past their last LDS reads
        float* sm = (float*)As;        // safe to reuse buf0 as scratch now
        if (l == 0) { sm[wv] = s; sm[4 + wv] = sq; }
        __syncthreads();
        if (t == 0) {
            atomicAdd(&statsOut[0], (double)(sm[0] + sm[1] + sm[2] + sm[3]));
            atomicAdd(&statsOut[1], (double)(sm[4] + sm[5] + sm[6] + sm[7]));
        }
    }
}

// ---------------------------------------------------------------------------
// bf16 MFMA flash attention (unchanged).
// ---------------------------------------------------------------------------
__global__ __launch_bounds__(256) void attn_mfma(const short* __restrict__ qkvb,
                                                 const short* __restrict__ Vtg,
                                                 short* __restrict__ head) {
    const int b  = blockIdx.y;
    const int q0 = blockIdx.x * 64;
    const int t  = threadIdx.x;
    const int w  = t >> 6;
    const int l  = t & 63;
    const int l15 = l & 15, lq = l >> 4;
    const int l7  = l & 7,  l8 = l >> 3;

    __shared__ short Ks[64][72];
    __shared__ short Vs[64][72];
    __shared__ short Ps[4][16][68];

    short8 qf[2];
    {
        const short* qrow = qkvb + (size_t)(b * SS + q0 + w * 16 + l15) * 256;
        qf[0] = *(const short8*)(qrow + lq * 8);
        qf[1] = *(const short8*)(qrow + 32 + lq * 8);
    }

    f32x4 acc[4];
#pragma unroll
    for (int mt = 0; mt < 4; ++mt) acc[mt] = {0.f, 0.f, 0.f, 0.f};
    float m_i = -INFINITY, l_i = 0.f;
    const float sc = 0.0450712500463f;   // log2(e)/32

    short8 kreg[2], vreg[2];
    {
        const short* kb = qkvb + (size_t)(b * SS) * 256 + 64;
        kreg[0] = *(const short8*)(kb + (size_t)(w * 8 + l8) * 256 + l7 * 8);
        kreg[1] = *(const short8*)(kb + (size_t)(32 + w * 8 + l8) * 256 + l7 * 8);
        const short* vb = Vtg + (size_t)b * 64 * SS;
        vreg[0] = *(const short8*)(vb + (size_t)(w * 8 + l8) * SS + l7 * 8);
        vreg[1] = *(const short8*)(vb + (size_t)(32 + w * 8 + l8) * SS + l7 * 8);
    }

    for (int kt = 0; kt < SS / 64; ++kt) {
        __syncthreads();
        *(short8*)&Ks[w * 8 + l8][l7 * 8]      = kreg[0];
        *(short8*)&Ks[32 + w * 8 + l8][l7 * 8] = kreg[1];
        *(short8*)&Vs[w * 8 + l8][l7 * 8]      = vreg[0];
        *(short8*)&Vs[32 + w * 8 + l8][l7 * 8] = vreg[1];
        if (kt + 1 < SS / 64) {
            const short* kb = qkvb + (size_t)(b * SS + (kt + 1) * 64) * 256 + 64;
            kreg[0] = *(const short8*)(kb + (size_t)(w * 8 + l8) * 256 + l7 * 8);
            kreg[1] = *(const short8*)(kb + (size_t)(32 + w * 8 + l8) * 256 + l7 * 8);
            const short* vb = Vtg + (size_t)b * 64 * SS + (kt + 1) * 64;
            vreg[0] = *(const short8*)(vb + (size_t)(w * 8 + l8) * SS + l7 * 8);
            vreg[1] = *(const short8*)(vb + (size_t)(32 + w * 8 + l8) * SS + l7 * 8);
        }
        __syncthreads();

        f32x4 st[4];
#pragma unroll
        for (int mt = 0; mt < 4; ++mt) st[mt] = {0.f, 0.f, 0.f, 0.f};
#pragma unroll
        for (int kc = 0; kc < 2; ++kc)
#pragma unroll
            for (int mt = 0; mt < 4; ++mt) {
                short8 kf = *(const short8*)&Ks[mt * 16 + l15][kc * 32 + lq * 8];
                st[mt] = __builtin_amdgcn_mfma_f32_16x16x32_bf16(kf, qf[kc], st[mt], 0, 0, 0);
            }
        float mx = m_i;
#pragma unroll
        for (int mt = 0; mt < 4; ++mt)
#pragma unroll
            for (int r = 0; r < 4; ++r) {
                st[mt][r] *= sc;
                mx = fmaxf(mx, st[mt][r]);
            }
        mx = fmaxf(mx, __shfl_xor(mx, 16));
        mx = fmaxf(mx, __shfl_xor(mx, 32));
        float alpha = exp2f(m_i - mx);
        float rs = 0.f;
#pragma unroll
        for (int mt = 0; mt < 4; ++mt) {
            s16x4 pk;
#pragma unroll
            for (int r = 0; r < 4; ++r) {
                float p = exp2f(st[mt][r] - mx);
                rs += p;
                pk[r] = f2b(p);
            }
            *(s16x4*)&Ps[w][l15][mt * 16 + lq * 4] = pk;
        }
        rs += __shfl_xor(rs, 16);
        rs += __shfl_xor(rs, 32);
        l_i = l_i * alpha + rs;
        m_i = mx;
#pragma unroll
        for (int mt = 0; mt < 4; ++mt)
#pragma unroll
            for (int r = 0; r < 4; ++r) acc[mt][r] *= alpha;

#pragma unroll
        for (int kc = 0; kc < 2; ++kc) {
            s16x4 p0 = *(const s16x4*)&Ps[w][l15][kc * 32 + lq * 8];
            s16x4 p1 = *(const s16x4*)&Ps[w][l15][kc * 32 + lq * 8 + 4];
            short8 pf = __builtin_shufflevector(p0, p1, 0, 1, 2, 3, 4, 5, 6, 7);
#pragma unroll
            for (int mt = 0; mt < 4; ++mt) {
                short8 vf = *(const short8*)&Vs[mt * 16 + l15][kc * 32 + lq * 8];
                acc[mt] = __builtin_amdgcn_mfma_f32_16x16x32_bf16(vf, pf, acc[mt], 0, 0, 0);
            }
        }
    }
    float inv = 1.0f / l_i;
    short* out = head + (size_t)(b * SS + q0 + w * 16 + l15) * 64;
#pragma unroll
    for (int mt = 0; mt < 4; ++mt) {
        s16x4 o;
#pragma unroll
        for (int r = 0; r < 4; ++r) o[r] = f2b(acc[mt][r] * inv);
        *(s16x4*)&out[mt * 16 + lq * 4] = o;
    }
}

// ---------------------------------------------------------------------------
// Final LN2 normalize: d_out fp32 = (b2f(T1) - mu)*rstd
// ---------------------------------------------------------------------------
__global__ __launch_bounds__(256) void lnfinal_kernel(const short* __restrict__ y,
                                                      float* __restrict__ out,
                                                      const double* __restrict__ red,
                                                      int n) {
    double mean = red[0] / n;
    double var  = red[1] / n - mean * mean;
    float mu   = (float)mean;
    float rstd = (float)(1.0 / sqrt(var + LN_EPS));
    for (int i = blockIdx.x * blockDim.x + threadIdx.x; i < n;
         i += gridDim.x * blockDim.x)
        out[i] = (b2f(y[i]) - mu) * rstd;
}

// ---------------------------------------------------------------------------
extern "C" void kernel_launch(void* const* d_in, const int* in_sizes, int n_in,
                              void* d_out, int out_size, void* d_ws, size_t ws_size,
                              hipStream_t stream) {
    const int*   ids = (const int*)d_in[0];
    const float* emb = (const float*)d_in[1];
    const float* Wq  = (const float*)d_in[2];
    const float* bq  = (const float*)d_in[3];
    const float* Wk  = (const float*)d_in[4];
    const float* bk  = (const float*)d_in[5];
    const float* Wv  = (const float*)d_in[6];
    const float* bv  = (const float*)d_in[7];
    const float* Wo  = (const float*)d_in[8];
    const float* bo  = (const float*)d_in[9];
    const float* W1  = (const float*)d_in[10];
    const float* b1  = (const float*)d_in[11];
    const float* W2  = (const float*)d_in[12];
    const float* b2  = (const float*)d_in[13];

    float* xout = (float*)d_out;                     // final output only
    char* w = (char*)d_ws;

    // Buffers (bf16 unless noted):
    //   hch  [16384][2048] (full) or [8192][2048] (chunked) -- FF hidden
    //   qkvb [16384][256], Vtg [8][64][2048], head [16384][64]  (alias in hch)
    //   T1   trunk y (rep input / FF2 output), T2 trunk z (outproj output)
    const bool big = ws_size >= (size_t)105195712 + 256;

    short *qkvb, *Vtg, *head, *T1, *T2, *hch, *WqkvT, *WoST, *W1T, *W2T;
    float *bqkv, *csq, *csw1; double* red;

    if (big) {
        hch   = (short*)(w + 0);                     // 64 MB
        qkvb  = (short*)(w + 0);                     //  8 MB (alias)
        Vtg   = (short*)(w + 8388608);               //  2 MB (alias)
        head  = (short*)(w + 10485760);              //  2 MB (alias)
        T1    = (short*)(w + 67108864);              // 16 MB
        T2    = (short*)(w + 83886080);              // 16 MB
        WqkvT = (short*)(w + 100663296);
        bqkv  = (float*)(w + 100925440);
        csq   = (float*)(w + 100926464);
        WoST  = (short*)(w + 100927488);
        W1T   = (short*)(w + 100993024);
        csw1  = (float*)(w + 103090176);
        W2T   = (short*)(w + 103098368);
        red   = (double*)(w + 105195520);
    } else {
        hch   = (short*)(w + 0);                     // 32 MB (M=8192 chunks)
        qkvb  = (short*)(w + 0);
        Vtg   = (short*)(w + 8388608);
        head  = (short*)(w + 10485760);
        T1    = (short*)(w + 33554432);
        T2    = (short*)(w + 50331648);
        WqkvT = (short*)(w + 67108864);
        bqkv  = (float*)(w + 67371008);
        csq   = (float*)(w + 67372032);
        WoST  = (short*)(w + 67373056);
        W1T   = (short*)(w + 67438592);
        csw1  = (float*)(w + 69535744);
        W2T   = (short*)(w + 69543936);
        red   = (double*)(w + 71641088);
    }

    // ---- setup (once per launch) ----
    packqkvT_kernel<<<(256 * 512 + 255) / 256, 256, 0, stream>>>(Wq, Wk, Wv, bq, bk, bv, WqkvT, bqkv);
    wosumT_kernel<<<(512 * 64 + 255) / 256, 256, 0, stream>>>(Wo, WoST);
    transpose_b16<<<dim3(2048 / 32, 512 / 32), 256, 0, stream>>>(W1, W1T, 512, 2048);
    transpose_b16<<<dim3(512 / 32, 2048 / 32), 256, 0, stream>>>(W2, W2T, 2048, 512);
    colsum_kernel<<<9, 256, 0, stream>>>(WqkvT, W1T, csq, csw1);
    embed_kernel<<<NTOT / 256, 256, 0, stream>>>(ids, emb, T1, red);

    for (int rep = 0; rep < 6; ++rep) {
        const double* sprev = rep ? red + 4 * (rep - 1) + 2 : nullptr;  // LN2 stats of prev rep
        double* red1 = red + 4 * rep;        // LN1 stats (over z = outproj out)
        double* red2 = red + 4 * rep + 2;    // LN2 stats (over y' = FF2 out)

        // QKV: LN2-folded  qkvb = LN(T1) @ Wqkv + bqkv   [16384][256]
        gemm_mfma<false, false, false, true, 64, 128, 64, 2><<<dim3(256, 2), 256, 0, stream>>>(
            T1, WqkvT, bqkv, csq, nullptr, qkvb, sprev, nullptr, ROWS, 256, DM);
        // V transpose
        vtrans_kernel<<<dim3(SS / 32, 2, BB), 256, 0, stream>>>(qkvb, Vtg);
        // flash attention -> head
        attn_mfma<<<dim3(SS / 64, BB), 256, 0, stream>>>(qkvb, Vtg, head);
        // out-proj: T2 = head @ WoS + bo + LN(T1); stats -> red1
        gemm_mfma<false, true, true, false, 64, 128, 64, 2><<<dim3(256, 4), 256, 0, stream>>>(
            head, WoST, bo, nullptr, T1, T2, sprev, red1, ROWS, DM, DK);
        // FF (LN1 folded into FF1 8-phase; FF2 8-wave 128x256 3buf)
        if (big) {
            gemm_ff1_8p<<<dim3(64, 8), 512, 0, stream>>>(
                T2, W1T, b1, csw1, hch, red1, ROWS, DFF);
            gemm_ff2_8w<<<dim3(128, 2), 512, 0, stream>>>(
                hch, W2T, b2, T2, T1, red1, red2, ROWS, DM, DFF);
        } else {
            for (int c = 0; c < 2; ++c) {
                const size_t off = (size_t)c * 8192 * DM;
                gemm_ff1_8p<<<dim3(32, 8), 512, 0, stream>>>(
                    T2 + off, W1T, b1, csw1, hch, red1, 8192, DFF);
                gemm_mfma<false, true, true, false, 64, 256, 32, 3><<<dim3(128, 2), 256, 0, stream>>>(
                    hch, W2T, b2, nullptr, T2 + off, T1 + off, red1, red2, 8192, DM, DFF);
            }
        }
    }
    // final LN2 normalize -> fp32 output
    lnfinal_kernel<<<4096, 256, 0, stream>>>(T1, xout, red + 4 * 5 + 2, NTOT);
}